// Round 1
// baseline (1817.324 us; speedup 1.0000x reference)
//
#include <hip/hip_runtime.h>
#include <math.h>

#define NB 16
#define NC 512
#define NPIX 4096
#define NK 64

// ---------------- zero accumulators ----------------
__global__ void zero_acc(float* __restrict__ p, int n) {
  int i = blockIdx.x * 256 + threadIdx.x;
  if (i < n) p[i] = 0.f;
}

// ---------------- 512x512 @ 512x4096 GEMM (conv1/conv2) ----------------
// O[b][m][n] = sum_c W[m][c] * X[b][c][n] (+ bias[m])
__global__ __launch_bounds__(256) void gemm512(
    const float* __restrict__ W, const float* __restrict__ X,
    const float* __restrict__ bias, float* __restrict__ O) {
  __shared__ float As[16][128];  // A^T: As[k][m]
  __shared__ float Bs[16][128];  // Bs[k][n]
  const int b = blockIdx.z;
  const int m0 = blockIdx.y * 128;
  const int n0 = blockIdx.x * 128;
  const float* Xb = X + (size_t)b * NC * NPIX;
  float* Ob = O + (size_t)b * NC * NPIX;
  const int t = threadIdx.x;
  const int ty = t >> 4, tx = t & 15;

  float acc[8][8];
#pragma unroll
  for (int i = 0; i < 8; ++i)
#pragma unroll
    for (int j = 0; j < 8; ++j) acc[i][j] = 0.f;

  for (int k0 = 0; k0 < NC; k0 += 16) {
#pragma unroll
    for (int r = 0; r < 2; ++r) {
      int id = t + r * 256;
      int arow = id >> 2, akq = (id & 3) << 2;
      float4 av = *(const float4*)(W + (size_t)(m0 + arow) * NC + k0 + akq);
      As[akq + 0][arow] = av.x;
      As[akq + 1][arow] = av.y;
      As[akq + 2][arow] = av.z;
      As[akq + 3][arow] = av.w;
      int brow = id >> 5, bq = (id & 31) << 2;
      *(float4*)&Bs[brow][bq] =
          *(const float4*)(Xb + (size_t)(k0 + brow) * NPIX + n0 + bq);
    }
    __syncthreads();
#pragma unroll
    for (int kk = 0; kk < 16; ++kk) {
      float4 a0 = *(float4*)&As[kk][ty << 2];
      float4 a1 = *(float4*)&As[kk][64 + (ty << 2)];
      float4 b0 = *(float4*)&Bs[kk][tx << 2];
      float4 b1 = *(float4*)&Bs[kk][64 + (tx << 2)];
      float a[8] = {a0.x, a0.y, a0.z, a0.w, a1.x, a1.y, a1.z, a1.w};
      float bb[8] = {b0.x, b0.y, b0.z, b0.w, b1.x, b1.y, b1.z, b1.w};
#pragma unroll
      for (int i = 0; i < 8; ++i)
#pragma unroll
        for (int j = 0; j < 8; ++j) acc[i][j] = fmaf(a[i], bb[j], acc[i][j]);
    }
    __syncthreads();
  }
#pragma unroll
  for (int i = 0; i < 8; ++i) {
    int m = m0 + ((i < 4) ? (ty * 4 + i) : (64 + ty * 4 + (i - 4)));
    float bv = bias ? bias[m] : 0.f;
    float4 v0 = make_float4(acc[i][0] + bv, acc[i][1] + bv, acc[i][2] + bv,
                            acc[i][3] + bv);
    float4 v1 = make_float4(acc[i][4] + bv, acc[i][5] + bv, acc[i][6] + bv,
                            acc[i][7] + bv);
    *(float4*)(Ob + (size_t)m * NPIX + n0 + tx * 4) = v0;
    *(float4*)(Ob + (size_t)m * NPIX + n0 + 64 + tx * 4) = v1;
  }
}

// ---------------- E-step: S = Y^T mu, softmax over k, colsum ----------------
__global__ __launch_bounds__(256) void estep(
    const float* __restrict__ Y, const float* __restrict__ mu,
    size_t mu_bstride, float* __restrict__ Z, float* __restrict__ colsum,
    float* __restrict__ Zt) {
  __shared__ float Ys[16][64];
  __shared__ float Ms[16][64];
  __shared__ float zs[64][68];
  __shared__ float cs[64];
  const int b = blockIdx.y;
  const int n0 = blockIdx.x * 64;
  const float* Yb = Y + (size_t)b * NC * NPIX;
  const float* mub = mu + (size_t)b * mu_bstride;
  const int t = threadIdx.x;
  const int ty = t >> 4, tx = t & 15;
  const int lrow = t >> 4;
  const int lq = (t & 15) << 2;

  float acc[4][4];
#pragma unroll
  for (int i = 0; i < 4; ++i)
#pragma unroll
    for (int j = 0; j < 4; ++j) acc[i][j] = 0.f;

  for (int c0 = 0; c0 < NC; c0 += 16) {
    *(float4*)&Ys[lrow][lq] =
        *(const float4*)(Yb + (size_t)(c0 + lrow) * NPIX + n0 + lq);
    *(float4*)&Ms[lrow][lq] =
        *(const float4*)(mub + (size_t)(c0 + lrow) * NK + lq);
    __syncthreads();
#pragma unroll
    for (int cc = 0; cc < 16; ++cc) {
      float4 a = *(float4*)&Ys[cc][ty << 2];
      float4 m4 = *(float4*)&Ms[cc][tx << 2];
      float av[4] = {a.x, a.y, a.z, a.w};
      float mv[4] = {m4.x, m4.y, m4.z, m4.w};
#pragma unroll
      for (int i = 0; i < 4; ++i)
#pragma unroll
        for (int j = 0; j < 4; ++j) acc[i][j] = fmaf(av[i], mv[j], acc[i][j]);
    }
    __syncthreads();
  }

  // softmax over k within each row n (16 threads with same ty cooperate)
  float z[4][4];
  float pcs[4] = {0.f, 0.f, 0.f, 0.f};
#pragma unroll
  for (int i = 0; i < 4; ++i) {
    float mx = fmaxf(fmaxf(acc[i][0], acc[i][1]), fmaxf(acc[i][2], acc[i][3]));
    mx = fmaxf(mx, __shfl_xor(mx, 1));
    mx = fmaxf(mx, __shfl_xor(mx, 2));
    mx = fmaxf(mx, __shfl_xor(mx, 4));
    mx = fmaxf(mx, __shfl_xor(mx, 8));
    float s = 0.f;
#pragma unroll
    for (int j = 0; j < 4; ++j) {
      z[i][j] = __expf(acc[i][j] - mx);
      s += z[i][j];
    }
    s += __shfl_xor(s, 1);
    s += __shfl_xor(s, 2);
    s += __shfl_xor(s, 4);
    s += __shfl_xor(s, 8);
    float inv = 1.f / s;
#pragma unroll
    for (int j = 0; j < 4; ++j) {
      z[i][j] *= inv;
      pcs[j] += z[i][j];
    }
  }

  float* Zb = Z + ((size_t)b * NPIX + n0) * NK;
#pragma unroll
  for (int i = 0; i < 4; ++i)
    *(float4*)&Zb[(size_t)(ty * 4 + i) * NK + tx * 4] =
        make_float4(z[i][0], z[i][1], z[i][2], z[i][3]);

  if (t < 64) cs[t] = 0.f;
  __syncthreads();
#pragma unroll
  for (int j = 0; j < 4; ++j) atomicAdd(&cs[tx * 4 + j], pcs[j]);
  __syncthreads();
  if (t < 64) atomicAdd(&colsum[b * NK + t], cs[t]);

  if (Zt) {  // final stage: also emit z transposed [b][k][n] (output z_t)
#pragma unroll
    for (int i = 0; i < 4; ++i)
#pragma unroll
      for (int j = 0; j < 4; ++j) zs[tx * 4 + j][ty * 4 + i] = z[i][j];
    __syncthreads();
    float* ZTb = Zt + (size_t)b * NK * NPIX + n0;
#pragma unroll
    for (int rr = 0; rr < 4; ++rr) {
      int krow = (t >> 4) + rr * 16;
      int ncol = (t & 15) * 4;
      *(float4*)(ZTb + (size_t)krow * NPIX + ncol) = *(float4*)&zs[krow][ncol];
    }
  }
}

// ---------------- M-step: mu_raw = Y z_, plus sumsq over c ----------------
__global__ __launch_bounds__(256) void mstep(
    const float* __restrict__ Y, const float* __restrict__ Z,
    const float* __restrict__ colsum, float* __restrict__ Mo,
    float* __restrict__ sumsq) {
  __shared__ float Ys[32][68];  // transposed: Ys[n][c]
  __shared__ float Zs[32][64];  // Zs[n][k]
  __shared__ float invc[64];
  __shared__ float ss[64];
  const int b = blockIdx.y;
  const int c0 = blockIdx.x * 64;
  const int t = threadIdx.x;
  const int ty = t >> 4, tx = t & 15;
  if (t < 64) {
    invc[t] = 1.f / (1e-6f + colsum[b * NK + t]);
    ss[t] = 0.f;
  }
  const float* Yb = Y + (size_t)b * NC * NPIX + (size_t)c0 * NPIX;
  const float* Zb = Z + (size_t)b * NPIX * NK;

  float acc[4][4];
#pragma unroll
  for (int i = 0; i < 4; ++i)
#pragma unroll
    for (int j = 0; j < 4; ++j) acc[i][j] = 0.f;

  for (int nb = 0; nb < NPIX; nb += 32) {
#pragma unroll
    for (int r = 0; r < 2; ++r) {
      int id = t + r * 256;
      int yc = id >> 3, ynq = (id & 7) << 2;
      float4 yv = *(const float4*)(Yb + (size_t)yc * NPIX + nb + ynq);
      Ys[ynq + 0][yc] = yv.x;
      Ys[ynq + 1][yc] = yv.y;
      Ys[ynq + 2][yc] = yv.z;
      Ys[ynq + 3][yc] = yv.w;
      int zn = id >> 4, zkq = (id & 15) << 2;
      *(float4*)&Zs[zn][zkq] =
          *(const float4*)(Zb + (size_t)(nb + zn) * NK + zkq);
    }
    __syncthreads();
#pragma unroll
    for (int nn = 0; nn < 32; ++nn) {
      float4 a = *(float4*)&Ys[nn][ty << 2];
      float4 zk = *(float4*)&Zs[nn][tx << 2];
      float av[4] = {a.x, a.y, a.z, a.w};
      float zv[4] = {zk.x, zk.y, zk.z, zk.w};
#pragma unroll
      for (int i = 0; i < 4; ++i)
#pragma unroll
        for (int j = 0; j < 4; ++j) acc[i][j] = fmaf(av[i], zv[j], acc[i][j]);
    }
    __syncthreads();
  }

  float pss[4] = {0.f, 0.f, 0.f, 0.f};
  float* Mob = Mo + ((size_t)b * NC + c0) * NK;
#pragma unroll
  for (int i = 0; i < 4; ++i) {
    float v[4];
#pragma unroll
    for (int j = 0; j < 4; ++j) {
      v[j] = acc[i][j] * invc[tx * 4 + j];
      pss[j] += v[j] * v[j];
    }
    *(float4*)&Mob[(size_t)(ty * 4 + i) * NK + tx * 4] =
        make_float4(v[0], v[1], v[2], v[3]);
  }
#pragma unroll
  for (int j = 0; j < 4; ++j) atomicAdd(&ss[tx * 4 + j], pss[j]);
  __syncthreads();
  if (t < 64) atomicAdd(&sumsq[b * NK + t], ss[t]);
}

// ---------------- normalize mu columns: mu /= (1e-6 + ||mu||) ----------------
__global__ void munorm(float* __restrict__ Mo, const float* __restrict__ sumsq) {
  int i = blockIdx.x * 256 + threadIdx.x;  // < 16*512*64
  int k = i & 63;
  int b = i >> 15;
  Mo[i] *= 1.f / (1e-6f + sqrtf(sumsq[b * NK + k]));
}

// ---------------- reconstruction: xr = relu(mu z^T) ----------------
__global__ __launch_bounds__(256) void recon(
    const float* __restrict__ Mo, const float* __restrict__ Z,
    float* __restrict__ XR) {
  __shared__ float Ms[64][68];  // Ms[k][c]
  __shared__ float Zs[64][68];  // Zs[k][n]
  const int b = blockIdx.z, c0 = blockIdx.y * 64, n0 = blockIdx.x * 64;
  const int t = threadIdx.x, ty = t >> 4, tx = t & 15;
  const float* Mb = Mo + (size_t)b * NC * NK;
  const float* Zb = Z + (size_t)b * NPIX * NK;
#pragma unroll
  for (int r = 0; r < 4; ++r) {
    int id = t + r * 256;
    int rc = id >> 4, kq = (id & 15) << 2;
    float4 mv = *(const float4*)(Mb + (size_t)(c0 + rc) * NK + kq);
    Ms[kq + 0][rc] = mv.x;
    Ms[kq + 1][rc] = mv.y;
    Ms[kq + 2][rc] = mv.z;
    Ms[kq + 3][rc] = mv.w;
    float4 zv = *(const float4*)(Zb + (size_t)(n0 + rc) * NK + kq);
    Zs[kq + 0][rc] = zv.x;
    Zs[kq + 1][rc] = zv.y;
    Zs[kq + 2][rc] = zv.z;
    Zs[kq + 3][rc] = zv.w;
  }
  __syncthreads();
  float acc[4][4];
#pragma unroll
  for (int i = 0; i < 4; ++i)
#pragma unroll
    for (int j = 0; j < 4; ++j) acc[i][j] = 0.f;
#pragma unroll 8
  for (int kk = 0; kk < 64; ++kk) {
    float4 a = *(float4*)&Ms[kk][ty << 2];
    float4 zv4 = *(float4*)&Zs[kk][tx << 2];
    float av[4] = {a.x, a.y, a.z, a.w};
    float zv[4] = {zv4.x, zv4.y, zv4.z, zv4.w};
#pragma unroll
    for (int i = 0; i < 4; ++i)
#pragma unroll
      for (int j = 0; j < 4; ++j) acc[i][j] = fmaf(av[i], zv[j], acc[i][j]);
  }
  float* XRb = XR + (size_t)b * NC * NPIX;
#pragma unroll
  for (int i = 0; i < 4; ++i) {
    float4 v = make_float4(fmaxf(acc[i][0], 0.f), fmaxf(acc[i][1], 0.f),
                           fmaxf(acc[i][2], 0.f), fmaxf(acc[i][3], 0.f));
    *(float4*)(XRb + (size_t)(c0 + ty * 4 + i) * NPIX + n0 + tx * 4) = v;
  }
}

// ---------------- BN stats: per-channel sum / sumsq over (b, n) ----------------
__global__ __launch_bounds__(256) void bn_stats(const float* __restrict__ X2,
                                                float* __restrict__ bsum,
                                                float* __restrict__ bss) {
  const int o = blockIdx.x, b = blockIdx.y;
  const int t = threadIdx.x;
  const float* base = X2 + ((size_t)b * NC + o) * NPIX;
  float s = 0.f, q = 0.f;
#pragma unroll
  for (int r = 0; r < 4; ++r) {
    float4 v = *(const float4*)(base + (size_t)(t + r * 256) * 4);
    s += v.x + v.y + v.z + v.w;
    q += v.x * v.x + v.y * v.y + v.z * v.z + v.w * v.w;
  }
#pragma unroll
  for (int m = 1; m < 64; m <<= 1) {
    s += __shfl_xor(s, m);
    q += __shfl_xor(q, m);
  }
  __shared__ float rs[4], rq[4];
  int w = t >> 6;
  if ((t & 63) == 0) {
    rs[w] = s;
    rq[w] = q;
  }
  __syncthreads();
  if (t == 0) {
    atomicAdd(&bsum[o], rs[0] + rs[1] + rs[2] + rs[3]);
    atomicAdd(&bss[o], rq[0] + rq[1] + rq[2] + rq[3]);
  }
}

// ---------------- BN finalize + residual + relu (in place on d_out) ----------------
__global__ __launch_bounds__(256) void bn_fin(
    const float* __restrict__ X2, const float* __restrict__ Xin,
    const float* __restrict__ bsum, const float* __restrict__ bss,
    const float* __restrict__ gamma, const float* __restrict__ beta,
    float* __restrict__ out) {
  const size_t total4 = (size_t)NB * NC * NPIX / 4;
  for (size_t i4 = (size_t)blockIdx.x * 256 + threadIdx.x; i4 < total4;
       i4 += (size_t)gridDim.x * 256) {
    size_t i = i4 * 4;
    int o = (int)((i >> 12) & 511);
    float mean = bsum[o] * (1.f / 65536.f);
    float var = bss[o] * (1.f / 65536.f) - mean * mean;
    float inv = rsqrtf(var + 1e-5f) * gamma[o];
    float sh = beta[o] - mean * inv;
    float4 v = *(const float4*)(X2 + i);
    float4 xo = *(const float4*)(Xin + i);
    float4 r;
    r.x = fmaxf(fmaf(v.x, inv, sh) + xo.x, 0.f);
    r.y = fmaxf(fmaf(v.y, inv, sh) + xo.y, 0.f);
    r.z = fmaxf(fmaf(v.z, inv, sh) + xo.z, 0.f);
    r.w = fmaxf(fmaf(v.w, inv, sh) + xo.w, 0.f);
    *(float4*)(out + i) = r;
  }
}

extern "C" void kernel_launch(void* const* d_in, const int* in_sizes, int n_in,
                              void* d_out, int out_size, void* d_ws,
                              size_t ws_size, hipStream_t stream) {
  const float* x = (const float*)d_in[0];      // [16,512,64,64]
  const float* w1 = (const float*)d_in[1];     // [512,512]
  const float* b1 = (const float*)d_in[2];     // [512]
  const float* w2 = (const float*)d_in[3];     // [512,512]
  const float* gamma = (const float*)d_in[4];  // [512]
  const float* beta = (const float*)d_in[5];   // [512]
  const float* mu0 = (const float*)d_in[6];    // [1,512,64]

  float* out = (float*)d_out;                       // [16,512,4096]
  float* mu_out = out + (size_t)NB * NC * NPIX;     // [16,512,64]
  float* zt_out = mu_out + (size_t)NB * NC * NK;    // [16,64,4096]

  float* ws = (float*)d_ws;
  float* Y = ws;                                    // [16,512,4096] conv1 out / xr
  float* Z = Y + (size_t)NB * NC * NPIX;            // [16,4096,64]
  float* accbase = Z + (size_t)NB * NPIX * NK;      // accumulators
  // layout: colsum[3][16*64], sumsq[3][16*64], bnsum[512], bnss[512]
  float* bnsum = accbase + 6 * 1024;
  float* bnss = bnsum + 512;

  zero_acc<<<dim3(28), dim3(256), 0, stream>>>(accbase, 7168);

  // conv1: Y = W1 @ x + b1
  gemm512<<<dim3(32, 4, 16), dim3(256), 0, stream>>>(w1, x, b1, Y);

  for (int s = 0; s < 3; ++s) {
    float* cs = accbase + s * 1024;
    float* sq = accbase + 3072 + s * 1024;
    const float* mu_in = (s == 0) ? mu0 : mu_out;
    size_t mstride = (s == 0) ? 0 : (size_t)NC * NK;
    estep<<<dim3(64, 16), dim3(256), 0, stream>>>(
        Y, mu_in, mstride, Z, cs, (s == 2) ? zt_out : (float*)nullptr);
    mstep<<<dim3(8, 16), dim3(256), 0, stream>>>(Y, Z, cs, mu_out, sq);
    munorm<<<dim3(2048), dim3(256), 0, stream>>>(mu_out, sq);
  }

  // xr = relu(mu z^T) -> overwrite Y
  recon<<<dim3(64, 8, 16), dim3(256), 0, stream>>>(mu_out, Z, Y);

  // conv2: x2 = W2 @ xr -> stage in d_out's `out` region
  gemm512<<<dim3(32, 4, 16), dim3(256), 0, stream>>>(w2, Y, nullptr, out);

  bn_stats<<<dim3(512, 16), dim3(256), 0, stream>>>(out, bnsum, bnss);
  bn_fin<<<dim3(8192), dim3(256), 0, stream>>>(out, x, bnsum, bnss, gamma,
                                               beta, out);
}

// Round 2
// 1442.439 us; speedup vs baseline: 1.2599x; 1.2599x over previous
//
#include <hip/hip_runtime.h>
#include <math.h>

#define NB 16
#define NC 512
#define NPIX 4096
#define NK 64

typedef __attribute__((ext_vector_type(8))) short short8;
typedef __attribute__((ext_vector_type(4))) float f32x4;

#define GLD16(gp, lp)                                                   \
  __builtin_amdgcn_global_load_lds(                                     \
      (const __attribute__((address_space(1))) void*)(gp),              \
      (__attribute__((address_space(3))) void*)(lp), 16, 0, 0)

__device__ inline ushort f2bf(float f) {
  unsigned u = __float_as_uint(f);
  unsigned r = u + 0x7FFFu + ((u >> 16) & 1u);
  return (ushort)(r >> 16);
}
__device__ inline float bf2f(ushort h) {
  return __uint_as_float((unsigned)h << 16);
}

// ---------------- zero accumulators ----------------
__global__ void zero_acc(float* __restrict__ p, int n) {
  int i = blockIdx.x * 256 + threadIdx.x;
  if (i < n) p[i] = 0.f;
}

// ---------------- W fp32 -> bf16 hi/lo ----------------
__global__ void wsplit(const float* __restrict__ W, ushort* __restrict__ Hi,
                       ushort* __restrict__ Lo) {
  int i = (blockIdx.x * 256 + threadIdx.x) * 4;
  float4 v = *(const float4*)(W + i);
  ushort4 h, l;
  h.x = f2bf(v.x); l.x = f2bf(v.x - bf2f(h.x));
  h.y = f2bf(v.y); l.y = f2bf(v.y - bf2f(h.y));
  h.z = f2bf(v.z); l.z = f2bf(v.z - bf2f(h.z));
  h.w = f2bf(v.w); l.w = f2bf(v.w - bf2f(h.w));
  *(ushort4*)(Hi + i) = h;
  *(ushort4*)(Lo + i) = l;
}

// ---------------- x [b][c][n] fp32 -> Xt [b][n][c] bf16 hi/lo ----------------
__global__ __launch_bounds__(256) void xtsplit(const float* __restrict__ X,
                                               ushort* __restrict__ Hi,
                                               ushort* __restrict__ Lo) {
  __shared__ float T[64][65];
  const int b = blockIdx.z, c0 = blockIdx.y * 64, n0 = blockIdx.x * 64;
  const int t = threadIdx.x;
  const float* Xb = X + ((size_t)b * NC + c0) * NPIX + n0;
#pragma unroll
  for (int r = 0; r < 4; ++r) {
    int lin = t + r * 256;
    int cl = lin >> 4, nq = (lin & 15) * 4;
    float4 v = *(const float4*)(Xb + (size_t)cl * NPIX + nq);
    T[cl][nq + 0] = v.x;
    T[cl][nq + 1] = v.y;
    T[cl][nq + 2] = v.z;
    T[cl][nq + 3] = v.w;
  }
  __syncthreads();
#pragma unroll
  for (int r = 0; r < 4; ++r) {
    int lin = t + r * 256;
    int nl = lin >> 4, cq = (lin & 15) * 4;
    ushort4 h, l;
    float v0 = T[cq + 0][nl], v1 = T[cq + 1][nl], v2 = T[cq + 2][nl],
          v3 = T[cq + 3][nl];
    h.x = f2bf(v0); l.x = f2bf(v0 - bf2f(h.x));
    h.y = f2bf(v1); l.y = f2bf(v1 - bf2f(h.y));
    h.z = f2bf(v2); l.z = f2bf(v2 - bf2f(h.z));
    h.w = f2bf(v3); l.w = f2bf(v3 - bf2f(h.w));
    size_t off = ((size_t)b * NPIX + n0 + nl) * NC + c0 + cq;
    *(ushort4*)(Hi + off) = h;
    *(ushort4*)(Lo + off) = l;
  }
}

// ---------------- split-bf16 MFMA GEMM: O[b][m][n] = sum_c W[m][c] Xt[b][n][c]
// 3 passes: Whi*Xhi + Whi*Xlo + Wlo*Xhi. 128x128 tile, BK=64, 4 waves.
__global__ __launch_bounds__(256) void gemm_split(
    const ushort* __restrict__ Whi, const ushort* __restrict__ Wlo,
    const ushort* __restrict__ Xhi, const ushort* __restrict__ Xlo,
    const float* __restrict__ bias, float* __restrict__ O) {
  __shared__ short As[128 * 64];  // [m][k], 16B slot s of row r stored at s^(r&7)
  __shared__ short Bs[128 * 64];  // [n][k], same swizzle
  const int b = blockIdx.z;
  const int m0 = blockIdx.y * 128;
  const int n0 = blockIdx.x * 128;
  const int t = threadIdx.x;
  const int lane = t & 63, wid = t >> 6;
  const int wr = wid >> 1, wc = wid & 1;

  const ushort* Xb_hi = Xhi + (size_t)b * NPIX * NC;
  const ushort* Xb_lo = Xlo + (size_t)b * NPIX * NC;
  const ushort* Asrc[3] = {Whi, Whi, Wlo};
  const ushort* Bsrc[3] = {Xb_hi, Xb_lo, Xb_hi};

  f32x4 acc[4][4];
#pragma unroll
  for (int i = 0; i < 4; ++i)
#pragma unroll
    for (int j = 0; j < 4; ++j) acc[i][j] = (f32x4){0.f, 0.f, 0.f, 0.f};

  const int s_r = lane >> 3;  // row within 8-row chunk
  const int s_p = lane & 7;   // physical 16B slot this lane fills

  for (int p = 0; p < 3; ++p) {
    const ushort* Ap = Asrc[p];
    const ushort* Bp = Bsrc[p];
    for (int k0 = 0; k0 < NC; k0 += 64) {
#pragma unroll
      for (int i = 0; i < 4; ++i) {
        int ch = wid * 4 + i;             // 16 chunks of 8 rows x 128B
        int r = ch * 8 + s_r;             // tile row
        int ls = s_p ^ (r & 7);           // logical slot that lands here
        GLD16(Ap + (size_t)(m0 + r) * NC + k0 + ls * 8, (short*)As + ch * 512);
        GLD16(Bp + (size_t)(n0 + r) * NC + k0 + ls * 8, (short*)Bs + ch * 512);
      }
      __syncthreads();
#pragma unroll
      for (int kk = 0; kk < 2; ++kk) {
        short8 af[4], bfr[4];
#pragma unroll
        for (int i = 0; i < 4; ++i) {
          int row = wr * 64 + i * 16 + (lane & 15);
          int ph = (kk * 4 + (lane >> 4)) ^ (row & 7);
          af[i] = *(const short8*)(As + row * 64 + ph * 8);
          int col = wc * 64 + i * 16 + (lane & 15);
          int phb = (kk * 4 + (lane >> 4)) ^ (col & 7);
          bfr[i] = *(const short8*)(Bs + col * 64 + phb * 8);
        }
#pragma unroll
        for (int i = 0; i < 4; ++i)
#pragma unroll
          for (int j = 0; j < 4; ++j)
            acc[i][j] = __builtin_amdgcn_mfma_f32_16x16x32_bf16(
                af[i], bfr[j], acc[i][j], 0, 0, 0);
      }
      __syncthreads();
    }
  }

  float* Ob = O + (size_t)b * NC * NPIX;
  const int cb = n0 + wc * 64 + (lane & 15);
  const int rb = m0 + wr * 64 + (lane >> 4) * 4;
#pragma unroll
  for (int i = 0; i < 4; ++i) {
#pragma unroll
    for (int q = 0; q < 4; ++q) {
      int r = rb + i * 16 + q;
      float bv = bias ? bias[r] : 0.f;
      float* orow = Ob + (size_t)r * NPIX;
#pragma unroll
      for (int j = 0; j < 4; ++j) orow[cb + j * 16] = acc[i][j][q] + bv;
    }
  }
}

// ---------------- E-step: S = Y^T mu, softmax over k, colsum ----------------
__global__ __launch_bounds__(256) void estep(
    const float* __restrict__ Y, const float* __restrict__ mu,
    size_t mu_bstride, float* __restrict__ Z, float* __restrict__ colsum,
    float* __restrict__ Zt) {
  __shared__ float Ys[16][64];
  __shared__ float Ms[16][64];
  __shared__ float zs[64][68];
  __shared__ float cs[64];
  const int b = blockIdx.y;
  const int n0 = blockIdx.x * 64;
  const float* Yb = Y + (size_t)b * NC * NPIX;
  const float* mub = mu + (size_t)b * mu_bstride;
  const int t = threadIdx.x;
  const int ty = t >> 4, tx = t & 15;
  const int lrow = t >> 4;
  const int lq = (t & 15) << 2;

  float acc[4][4];
#pragma unroll
  for (int i = 0; i < 4; ++i)
#pragma unroll
    for (int j = 0; j < 4; ++j) acc[i][j] = 0.f;

  for (int c0 = 0; c0 < NC; c0 += 16) {
    *(float4*)&Ys[lrow][lq] =
        *(const float4*)(Yb + (size_t)(c0 + lrow) * NPIX + n0 + lq);
    *(float4*)&Ms[lrow][lq] =
        *(const float4*)(mub + (size_t)(c0 + lrow) * NK + lq);
    __syncthreads();
#pragma unroll
    for (int cc = 0; cc < 16; ++cc) {
      float4 a = *(float4*)&Ys[cc][ty << 2];
      float4 m4 = *(float4*)&Ms[cc][tx << 2];
      float av[4] = {a.x, a.y, a.z, a.w};
      float mv[4] = {m4.x, m4.y, m4.z, m4.w};
#pragma unroll
      for (int i = 0; i < 4; ++i)
#pragma unroll
        for (int j = 0; j < 4; ++j) acc[i][j] = fmaf(av[i], mv[j], acc[i][j]);
    }
    __syncthreads();
  }

  float z[4][4];
  float pcs[4] = {0.f, 0.f, 0.f, 0.f};
#pragma unroll
  for (int i = 0; i < 4; ++i) {
    float mx = fmaxf(fmaxf(acc[i][0], acc[i][1]), fmaxf(acc[i][2], acc[i][3]));
    mx = fmaxf(mx, __shfl_xor(mx, 1));
    mx = fmaxf(mx, __shfl_xor(mx, 2));
    mx = fmaxf(mx, __shfl_xor(mx, 4));
    mx = fmaxf(mx, __shfl_xor(mx, 8));
    float s = 0.f;
#pragma unroll
    for (int j = 0; j < 4; ++j) {
      z[i][j] = __expf(acc[i][j] - mx);
      s += z[i][j];
    }
    s += __shfl_xor(s, 1);
    s += __shfl_xor(s, 2);
    s += __shfl_xor(s, 4);
    s += __shfl_xor(s, 8);
    float inv = 1.f / s;
#pragma unroll
    for (int j = 0; j < 4; ++j) {
      z[i][j] *= inv;
      pcs[j] += z[i][j];
    }
  }

  float* Zb = Z + ((size_t)b * NPIX + n0) * NK;
#pragma unroll
  for (int i = 0; i < 4; ++i)
    *(float4*)&Zb[(size_t)(ty * 4 + i) * NK + tx * 4] =
        make_float4(z[i][0], z[i][1], z[i][2], z[i][3]);

  if (t < 64) cs[t] = 0.f;
  __syncthreads();
#pragma unroll
  for (int j = 0; j < 4; ++j) atomicAdd(&cs[tx * 4 + j], pcs[j]);
  __syncthreads();
  if (t < 64) atomicAdd(&colsum[b * NK + t], cs[t]);

  if (Zt) {
#pragma unroll
    for (int i = 0; i < 4; ++i)
#pragma unroll
      for (int j = 0; j < 4; ++j) zs[tx * 4 + j][ty * 4 + i] = z[i][j];
    __syncthreads();
    float* ZTb = Zt + (size_t)b * NK * NPIX + n0;
#pragma unroll
    for (int rr = 0; rr < 4; ++rr) {
      int krow = (t >> 4) + rr * 16;
      int ncol = (t & 15) * 4;
      *(float4*)(ZTb + (size_t)krow * NPIX + ncol) = *(float4*)&zs[krow][ncol];
    }
  }
}

// ---------------- M-step: mu_raw = Y z_, plus sumsq over c ----------------
__global__ __launch_bounds__(256) void mstep(
    const float* __restrict__ Y, const float* __restrict__ Z,
    const float* __restrict__ colsum, float* __restrict__ Mo,
    float* __restrict__ sumsq) {
  __shared__ float Ys[32][68];
  __shared__ float Zs[32][64];
  __shared__ float invc[64];
  __shared__ float ss[64];
  const int b = blockIdx.y;
  const int c0 = blockIdx.x * 64;
  const int t = threadIdx.x;
  const int ty = t >> 4, tx = t & 15;
  if (t < 64) {
    invc[t] = 1.f / (1e-6f + colsum[b * NK + t]);
    ss[t] = 0.f;
  }
  const float* Yb = Y + (size_t)b * NC * NPIX + (size_t)c0 * NPIX;
  const float* Zb = Z + (size_t)b * NPIX * NK;

  float acc[4][4];
#pragma unroll
  for (int i = 0; i < 4; ++i)
#pragma unroll
    for (int j = 0; j < 4; ++j) acc[i][j] = 0.f;

  for (int nb = 0; nb < NPIX; nb += 32) {
#pragma unroll
    for (int r = 0; r < 2; ++r) {
      int id = t + r * 256;
      int yc = id >> 3, ynq = (id & 7) << 2;
      float4 yv = *(const float4*)(Yb + (size_t)yc * NPIX + nb + ynq);
      Ys[ynq + 0][yc] = yv.x;
      Ys[ynq + 1][yc] = yv.y;
      Ys[ynq + 2][yc] = yv.z;
      Ys[ynq + 3][yc] = yv.w;
      int zn = id >> 4, zkq = (id & 15) << 2;
      *(float4*)&Zs[zn][zkq] =
          *(const float4*)(Zb + (size_t)(nb + zn) * NK + zkq);
    }
    __syncthreads();
#pragma unroll
    for (int nn = 0; nn < 32; ++nn) {
      float4 a = *(float4*)&Ys[nn][ty << 2];
      float4 zk = *(float4*)&Zs[nn][tx << 2];
      float av[4] = {a.x, a.y, a.z, a.w};
      float zv[4] = {zk.x, zk.y, zk.z, zk.w};
#pragma unroll
      for (int i = 0; i < 4; ++i)
#pragma unroll
        for (int j = 0; j < 4; ++j) acc[i][j] = fmaf(av[i], zv[j], acc[i][j]);
    }
    __syncthreads();
  }

  float pss[4] = {0.f, 0.f, 0.f, 0.f};
  float* Mob = Mo + ((size_t)b * NC + c0) * NK;
#pragma unroll
  for (int i = 0; i < 4; ++i) {
    float v[4];
#pragma unroll
    for (int j = 0; j < 4; ++j) {
      v[j] = acc[i][j] * invc[tx * 4 + j];
      pss[j] += v[j] * v[j];
    }
    *(float4*)&Mob[(size_t)(ty * 4 + i) * NK + tx * 4] =
        make_float4(v[0], v[1], v[2], v[3]);
  }
#pragma unroll
  for (int j = 0; j < 4; ++j) atomicAdd(&ss[tx * 4 + j], pss[j]);
  __syncthreads();
  if (t < 64) atomicAdd(&sumsq[b * NK + t], ss[t]);
}

// ---------------- normalize mu columns ----------------
__global__ void munorm(float* __restrict__ Mo, const float* __restrict__ sumsq) {
  int i = blockIdx.x * 256 + threadIdx.x;
  int k = i & 63;
  int b = i >> 15;
  Mo[i] *= 1.f / (1e-6f + sqrtf(sumsq[b * NK + k]));
}

// ---------------- reconstruction: xr = relu(mu z^T) -> bf16 hi/lo [b][n][c] ----
__global__ __launch_bounds__(256) void recon(
    const float* __restrict__ Mo, const float* __restrict__ Z,
    ushort* __restrict__ XtHi, ushort* __restrict__ XtLo) {
  __shared__ float Ms[64][68];
  __shared__ float Zs[64][68];
  const int b = blockIdx.z, c0 = blockIdx.y * 64, n0 = blockIdx.x * 64;
  const int t = threadIdx.x, ty = t >> 4, tx = t & 15;
  const float* Mb = Mo + (size_t)b * NC * NK;
  const float* Zb = Z + (size_t)b * NPIX * NK;
#pragma unroll
  for (int r = 0; r < 4; ++r) {
    int id = t + r * 256;
    int rc = id >> 4, kq = (id & 15) << 2;
    float4 mv = *(const float4*)(Mb + (size_t)(c0 + rc) * NK + kq);
    Ms[kq + 0][rc] = mv.x;
    Ms[kq + 1][rc] = mv.y;
    Ms[kq + 2][rc] = mv.z;
    Ms[kq + 3][rc] = mv.w;
    float4 zv = *(const float4*)(Zb + (size_t)(n0 + rc) * NK + kq);
    Zs[kq + 0][rc] = zv.x;
    Zs[kq + 1][rc] = zv.y;
    Zs[kq + 2][rc] = zv.z;
    Zs[kq + 3][rc] = zv.w;
  }
  __syncthreads();
  float acc[4][4];
#pragma unroll
  for (int i = 0; i < 4; ++i)
#pragma unroll
    for (int j = 0; j < 4; ++j) acc[i][j] = 0.f;
#pragma unroll 8
  for (int kk = 0; kk < 64; ++kk) {
    float4 a = *(float4*)&Ms[kk][ty << 2];
    float4 zv4 = *(float4*)&Zs[kk][tx << 2];
    float av[4] = {a.x, a.y, a.z, a.w};
    float zv[4] = {zv4.x, zv4.y, zv4.z, zv4.w};
#pragma unroll
    for (int i = 0; i < 4; ++i)
#pragma unroll
      for (int j = 0; j < 4; ++j) acc[i][j] = fmaf(av[i], zv[j], acc[i][j]);
  }
  // write transposed bf16 split: Xt[b][n][c], c contiguous
#pragma unroll
  for (int j = 0; j < 4; ++j) {
    float v0 = fmaxf(acc[0][j], 0.f), v1 = fmaxf(acc[1][j], 0.f);
    float v2 = fmaxf(acc[2][j], 0.f), v3 = fmaxf(acc[3][j], 0.f);
    ushort4 h, l;
    h.x = f2bf(v0); l.x = f2bf(v0 - bf2f(h.x));
    h.y = f2bf(v1); l.y = f2bf(v1 - bf2f(h.y));
    h.z = f2bf(v2); l.z = f2bf(v2 - bf2f(h.z));
    h.w = f2bf(v3); l.w = f2bf(v3 - bf2f(h.w));
    size_t off = ((size_t)b * NPIX + n0 + tx * 4 + j) * NC + c0 + ty * 4;
    *(ushort4*)(XtHi + off) = h;
    *(ushort4*)(XtLo + off) = l;
  }
}

// ---------------- BN stats ----------------
__global__ __launch_bounds__(256) void bn_stats(const float* __restrict__ X2,
                                                float* __restrict__ bsum,
                                                float* __restrict__ bss) {
  const int o = blockIdx.x, b = blockIdx.y;
  const int t = threadIdx.x;
  const float* base = X2 + ((size_t)b * NC + o) * NPIX;
  float s = 0.f, q = 0.f;
#pragma unroll
  for (int r = 0; r < 4; ++r) {
    float4 v = *(const float4*)(base + (size_t)(t + r * 256) * 4);
    s += v.x + v.y + v.z + v.w;
    q += v.x * v.x + v.y * v.y + v.z * v.z + v.w * v.w;
  }
#pragma unroll
  for (int m = 1; m < 64; m <<= 1) {
    s += __shfl_xor(s, m);
    q += __shfl_xor(q, m);
  }
  __shared__ float rs[4], rq[4];
  int w = t >> 6;
  if ((t & 63) == 0) {
    rs[w] = s;
    rq[w] = q;
  }
  __syncthreads();
  if (t == 0) {
    atomicAdd(&bsum[o], rs[0] + rs[1] + rs[2] + rs[3]);
    atomicAdd(&bss[o], rq[0] + rq[1] + rq[2] + rq[3]);
  }
}

// ---------------- BN finalize + residual + relu ----------------
__global__ __launch_bounds__(256) void bn_fin(
    const float* __restrict__ X2, const float* __restrict__ Xin,
    const float* __restrict__ bsum, const float* __restrict__ bss,
    const float* __restrict__ gamma, const float* __restrict__ beta,
    float* __restrict__ out) {
  const size_t total4 = (size_t)NB * NC * NPIX / 4;
  for (size_t i4 = (size_t)blockIdx.x * 256 + threadIdx.x; i4 < total4;
       i4 += (size_t)gridDim.x * 256) {
    size_t i = i4 * 4;
    int o = (int)((i >> 12) & 511);
    float mean = bsum[o] * (1.f / 65536.f);
    float var = bss[o] * (1.f / 65536.f) - mean * mean;
    float inv = rsqrtf(var + 1e-5f) * gamma[o];
    float sh = beta[o] - mean * inv;
    float4 v = *(const float4*)(X2 + i);
    float4 xo = *(const float4*)(Xin + i);
    float4 r;
    r.x = fmaxf(fmaf(v.x, inv, sh) + xo.x, 0.f);
    r.y = fmaxf(fmaf(v.y, inv, sh) + xo.y, 0.f);
    r.z = fmaxf(fmaf(v.z, inv, sh) + xo.z, 0.f);
    r.w = fmaxf(fmaf(v.w, inv, sh) + xo.w, 0.f);
    *(float4*)(out + i) = r;
  }
}

extern "C" void kernel_launch(void* const* d_in, const int* in_sizes, int n_in,
                              void* d_out, int out_size, void* d_ws,
                              size_t ws_size, hipStream_t stream) {
  const float* x = (const float*)d_in[0];
  const float* w1 = (const float*)d_in[1];
  const float* b1 = (const float*)d_in[2];
  const float* w2 = (const float*)d_in[3];
  const float* gamma = (const float*)d_in[4];
  const float* beta = (const float*)d_in[5];
  const float* mu0 = (const float*)d_in[6];

  float* out = (float*)d_out;                     // [16,512,4096]
  float* mu_out = out + (size_t)NB * NC * NPIX;   // [16,512,64]
  float* zt_out = mu_out + (size_t)NB * NC * NK;  // [16,64,4096]

  // Xt bf16 hi/lo scratch overlays the `out` region (dead until bn_fin).
  ushort* XtHi = (ushort*)out;
  ushort* XtLo = XtHi + (size_t)NB * NPIX * NC;

  float* ws = (float*)d_ws;
  float* Y = ws;                                // [16,512,4096] conv out / x2
  float* Z = Y + (size_t)NB * NC * NPIX;        // [16,4096,64]
  float* accbase = Z + (size_t)NB * NPIX * NK;  // colsum[3]|sumsq[3]|bn
  float* bnsum = accbase + 6 * 1024;
  float* bnss = bnsum + 512;
  ushort* W1hi = (ushort*)(accbase + 8192);
  ushort* W1lo = W1hi + NC * NC;
  ushort* W2hi = W1lo + NC * NC;
  ushort* W2lo = W2hi + NC * NC;

  zero_acc<<<dim3(28), dim3(256), 0, stream>>>(accbase, 7168);
  wsplit<<<dim3(256), dim3(256), 0, stream>>>(w1, W1hi, W1lo);
  wsplit<<<dim3(256), dim3(256), 0, stream>>>(w2, W2hi, W2lo);
  xtsplit<<<dim3(64, 8, 16), dim3(256), 0, stream>>>(x, XtHi, XtLo);

  // conv1: Y = W1 @ x + b1  (MFMA split-bf16)
  gemm_split<<<dim3(32, 4, 16), dim3(256), 0, stream>>>(W1hi, W1lo, XtHi, XtLo,
                                                        b1, Y);

  for (int s = 0; s < 3; ++s) {
    float* cs = accbase + s * 1024;
    float* sq = accbase + 3072 + s * 1024;
    const float* mu_in = (s == 0) ? mu0 : mu_out;
    size_t mstride = (s == 0) ? 0 : (size_t)NC * NK;
    estep<<<dim3(64, 16), dim3(256), 0, stream>>>(
        Y, mu_in, mstride, Z, cs, (s == 2) ? zt_out : (float*)nullptr);
    mstep<<<dim3(8, 16), dim3(256), 0, stream>>>(Y, Z, cs, mu_out, sq);
    munorm<<<dim3(2048), dim3(256), 0, stream>>>(mu_out, sq);
  }

  // xr = relu(mu z^T) -> bf16 hi/lo transposed (overwrites Xt region)
  recon<<<dim3(64, 8, 16), dim3(256), 0, stream>>>(mu_out, Z, XtHi, XtLo);

  // conv2: x2 = W2 @ xr -> Y region (free after recon)
  gemm_split<<<dim3(32, 4, 16), dim3(256), 0, stream>>>(W2hi, W2lo, XtHi, XtLo,
                                                        (const float*)nullptr,
                                                        Y);

  bn_stats<<<dim3(512, 16), dim3(256), 0, stream>>>(Y, bnsum, bnss);
  bn_fin<<<dim3(8192), dim3(256), 0, stream>>>(Y, x, bnsum, bnss, gamma, beta,
                                               out);
}

// Round 3
// 1210.665 us; speedup vs baseline: 1.5011x; 1.1914x over previous
//
#include <hip/hip_runtime.h>
#include <math.h>

#define NB 16
#define NC 512
#define NPIX 4096
#define NK 64

typedef __attribute__((ext_vector_type(8))) short short8;
typedef __attribute__((ext_vector_type(4))) float f32x4;

#define GLD16(gp, lp)                                                   \
  __builtin_amdgcn_global_load_lds(                                     \
      (const __attribute__((address_space(1))) void*)(gp),              \
      (__attribute__((address_space(3))) void*)(lp), 16, 0, 0)

__device__ inline ushort f2bf(float f) {
  unsigned u = __float_as_uint(f);
  unsigned r = u + 0x7FFFu + ((u >> 16) & 1u);
  return (ushort)(r >> 16);
}
__device__ inline float bf2f(ushort h) {
  return __uint_as_float((unsigned)h << 16);
}

// ---------------- zero accumulators ----------------
__global__ void zero_acc(float* __restrict__ p, int n) {
  int i = blockIdx.x * 256 + threadIdx.x;
  if (i < n) p[i] = 0.f;
}

// ---------------- W fp32 -> bf16 hi/lo ----------------
__global__ void wsplit(const float* __restrict__ W, ushort* __restrict__ Hi,
                       ushort* __restrict__ Lo) {
  int i = (blockIdx.x * 256 + threadIdx.x) * 4;
  float4 v = *(const float4*)(W + i);
  ushort4 h, l;
  h.x = f2bf(v.x); l.x = f2bf(v.x - bf2f(h.x));
  h.y = f2bf(v.y); l.y = f2bf(v.y - bf2f(h.y));
  h.z = f2bf(v.z); l.z = f2bf(v.z - bf2f(h.z));
  h.w = f2bf(v.w); l.w = f2bf(v.w - bf2f(h.w));
  *(ushort4*)(Hi + i) = h;
  *(ushort4*)(Lo + i) = l;
}

// ---------------- x [b][c][n] fp32 -> Xt [b][n][c] bf16 hi/lo ----------------
__global__ __launch_bounds__(256) void xtsplit(const float* __restrict__ X,
                                               ushort* __restrict__ Hi,
                                               ushort* __restrict__ Lo) {
  __shared__ float T[64][65];
  const int b = blockIdx.z, c0 = blockIdx.y * 64, n0 = blockIdx.x * 64;
  const int t = threadIdx.x;
  const float* Xb = X + ((size_t)b * NC + c0) * NPIX + n0;
#pragma unroll
  for (int r = 0; r < 4; ++r) {
    int lin = t + r * 256;
    int cl = lin >> 4, nq = (lin & 15) * 4;
    float4 v = *(const float4*)(Xb + (size_t)cl * NPIX + nq);
    T[cl][nq + 0] = v.x;
    T[cl][nq + 1] = v.y;
    T[cl][nq + 2] = v.z;
    T[cl][nq + 3] = v.w;
  }
  __syncthreads();
#pragma unroll
  for (int r = 0; r < 4; ++r) {
    int lin = t + r * 256;
    int nl = lin >> 4, cq = (lin & 15) * 4;
    ushort4 h, l;
    float v0 = T[cq + 0][nl], v1 = T[cq + 1][nl], v2 = T[cq + 2][nl],
          v3 = T[cq + 3][nl];
    h.x = f2bf(v0); l.x = f2bf(v0 - bf2f(h.x));
    h.y = f2bf(v1); l.y = f2bf(v1 - bf2f(h.y));
    h.z = f2bf(v2); l.z = f2bf(v2 - bf2f(h.z));
    h.w = f2bf(v3); l.w = f2bf(v3 - bf2f(h.w));
    size_t off = ((size_t)b * NPIX + n0 + nl) * NC + c0 + cq;
    *(ushort4*)(Hi + off) = h;
    *(ushort4*)(Lo + off) = l;
  }
}

// ---------------- split-bf16 MFMA GEMM: O[b][m][n] = sum_c W[m][c] Xt[b][n][c]
__global__ __launch_bounds__(256) void gemm_split(
    const ushort* __restrict__ Whi, const ushort* __restrict__ Wlo,
    const ushort* __restrict__ Xhi, const ushort* __restrict__ Xlo,
    const float* __restrict__ bias, float* __restrict__ O) {
  __shared__ short As[128 * 64];
  __shared__ short Bs[128 * 64];
  const int b = blockIdx.z;
  const int m0 = blockIdx.y * 128;
  const int n0 = blockIdx.x * 128;
  const int t = threadIdx.x;
  const int lane = t & 63, wid = t >> 6;
  const int wr = wid >> 1, wc = wid & 1;

  const ushort* Xb_hi = Xhi + (size_t)b * NPIX * NC;
  const ushort* Xb_lo = Xlo + (size_t)b * NPIX * NC;
  const ushort* Asrc[3] = {Whi, Whi, Wlo};
  const ushort* Bsrc[3] = {Xb_hi, Xb_lo, Xb_hi};

  f32x4 acc[4][4];
#pragma unroll
  for (int i = 0; i < 4; ++i)
#pragma unroll
    for (int j = 0; j < 4; ++j) acc[i][j] = (f32x4){0.f, 0.f, 0.f, 0.f};

  const int s_r = lane >> 3;
  const int s_p = lane & 7;

  for (int p = 0; p < 3; ++p) {
    const ushort* Ap = Asrc[p];
    const ushort* Bp = Bsrc[p];
    for (int k0 = 0; k0 < NC; k0 += 64) {
#pragma unroll
      for (int i = 0; i < 4; ++i) {
        int ch = wid * 4 + i;
        int r = ch * 8 + s_r;
        int ls = s_p ^ (r & 7);
        GLD16(Ap + (size_t)(m0 + r) * NC + k0 + ls * 8, (short*)As + ch * 512);
        GLD16(Bp + (size_t)(n0 + r) * NC + k0 + ls * 8, (short*)Bs + ch * 512);
      }
      __syncthreads();
#pragma unroll
      for (int kk = 0; kk < 2; ++kk) {
        short8 af[4], bfr[4];
#pragma unroll
        for (int i = 0; i < 4; ++i) {
          int row = wr * 64 + i * 16 + (lane & 15);
          int ph = (kk * 4 + (lane >> 4)) ^ (row & 7);
          af[i] = *(const short8*)(As + row * 64 + ph * 8);
          int col = wc * 64 + i * 16 + (lane & 15);
          int phb = (kk * 4 + (lane >> 4)) ^ (col & 7);
          bfr[i] = *(const short8*)(Bs + col * 64 + phb * 8);
        }
#pragma unroll
        for (int i = 0; i < 4; ++i)
#pragma unroll
          for (int j = 0; j < 4; ++j)
            acc[i][j] = __builtin_amdgcn_mfma_f32_16x16x32_bf16(
                af[i], bfr[j], acc[i][j], 0, 0, 0);
      }
      __syncthreads();
    }
  }

  float* Ob = O + (size_t)b * NC * NPIX;
  const int cb = n0 + wc * 64 + (lane & 15);
  const int rb = m0 + wr * 64 + (lane >> 4) * 4;
#pragma unroll
  for (int i = 0; i < 4; ++i) {
#pragma unroll
    for (int q = 0; q < 4; ++q) {
      int r = rb + i * 16 + q;
      float bv = bias ? bias[r] : 0.f;
      float* orow = Ob + (size_t)r * NPIX;
#pragma unroll
      for (int j = 0; j < 4; ++j) orow[cb + j * 16] = acc[i][j][q] + bv;
    }
  }
}

// ---------------- E-step: S = Y^T mu, softmax over k, colsum ----------------
__global__ __launch_bounds__(256) void estep(
    const float* __restrict__ Y, const float* __restrict__ mu,
    size_t mu_bstride, float* __restrict__ Z, float* __restrict__ colsum,
    float* __restrict__ Zt) {
  __shared__ float Ys[16][64];
  __shared__ float Ms[16][64];
  __shared__ float zs[64][68];
  __shared__ float cs[64];
  const int b = blockIdx.y;
  const int n0 = blockIdx.x * 64;
  const float* Yb = Y + (size_t)b * NC * NPIX;
  const float* mub = mu + (size_t)b * mu_bstride;
  const int t = threadIdx.x;
  const int ty = t >> 4, tx = t & 15;
  const int lrow = t >> 4;
  const int lq = (t & 15) << 2;

  float acc[4][4];
#pragma unroll
  for (int i = 0; i < 4; ++i)
#pragma unroll
    for (int j = 0; j < 4; ++j) acc[i][j] = 0.f;

  for (int c0 = 0; c0 < NC; c0 += 16) {
    *(float4*)&Ys[lrow][lq] =
        *(const float4*)(Yb + (size_t)(c0 + lrow) * NPIX + n0 + lq);
    *(float4*)&Ms[lrow][lq] =
        *(const float4*)(mub + (size_t)(c0 + lrow) * NK + lq);
    __syncthreads();
#pragma unroll
    for (int cc = 0; cc < 16; ++cc) {
      float4 a = *(float4*)&Ys[cc][ty << 2];
      float4 m4 = *(float4*)&Ms[cc][tx << 2];
      float av[4] = {a.x, a.y, a.z, a.w};
      float mv[4] = {m4.x, m4.y, m4.z, m4.w};
#pragma unroll
      for (int i = 0; i < 4; ++i)
#pragma unroll
        for (int j = 0; j < 4; ++j) acc[i][j] = fmaf(av[i], mv[j], acc[i][j]);
    }
    __syncthreads();
  }

  float z[4][4];
  float pcs[4] = {0.f, 0.f, 0.f, 0.f};
#pragma unroll
  for (int i = 0; i < 4; ++i) {
    float mx = fmaxf(fmaxf(acc[i][0], acc[i][1]), fmaxf(acc[i][2], acc[i][3]));
    mx = fmaxf(mx, __shfl_xor(mx, 1));
    mx = fmaxf(mx, __shfl_xor(mx, 2));
    mx = fmaxf(mx, __shfl_xor(mx, 4));
    mx = fmaxf(mx, __shfl_xor(mx, 8));
    float s = 0.f;
#pragma unroll
    for (int j = 0; j < 4; ++j) {
      z[i][j] = __expf(acc[i][j] - mx);
      s += z[i][j];
    }
    s += __shfl_xor(s, 1);
    s += __shfl_xor(s, 2);
    s += __shfl_xor(s, 4);
    s += __shfl_xor(s, 8);
    float inv = 1.f / s;
#pragma unroll
    for (int j = 0; j < 4; ++j) {
      z[i][j] *= inv;
      pcs[j] += z[i][j];
    }
  }

  float* Zb = Z + ((size_t)b * NPIX + n0) * NK;
#pragma unroll
  for (int i = 0; i < 4; ++i)
    *(float4*)&Zb[(size_t)(ty * 4 + i) * NK + tx * 4] =
        make_float4(z[i][0], z[i][1], z[i][2], z[i][3]);

  if (t < 64) cs[t] = 0.f;
  __syncthreads();
#pragma unroll
  for (int j = 0; j < 4; ++j) atomicAdd(&cs[tx * 4 + j], pcs[j]);
  __syncthreads();
  if (t < 64) atomicAdd(&colsum[b * NK + t], cs[t]);

  if (Zt) {
#pragma unroll
    for (int i = 0; i < 4; ++i)
#pragma unroll
      for (int j = 0; j < 4; ++j) zs[tx * 4 + j][ty * 4 + i] = z[i][j];
    __syncthreads();
    float* ZTb = Zt + (size_t)b * NK * NPIX + n0;
#pragma unroll
    for (int rr = 0; rr < 4; ++rr) {
      int krow = (t >> 4) + rr * 16;
      int ncol = (t & 15) * 4;
      *(float4*)(ZTb + (size_t)krow * NPIX + ncol) = *(float4*)&zs[krow][ncol];
    }
  }
}

// ---------------- M-step (split-N): Mraw[b][c][k] += sum_n Y[c][n] z_[n][k] ---
__global__ __launch_bounds__(256) void mstep(
    const float* __restrict__ Y, const float* __restrict__ Z,
    const float* __restrict__ colsum, float* __restrict__ Mraw) {
  __shared__ float Ys[32][68];
  __shared__ float Zs[32][64];
  __shared__ float invc[64];
  const int b = blockIdx.y;
  const int c0 = blockIdx.x * 64;
  const int nbase = blockIdx.z * 512;
  const int t = threadIdx.x;
  const int ty = t >> 4, tx = t & 15;
  if (t < 64) invc[t] = 1.f / (1e-6f + colsum[b * NK + t]);
  const float* Yb = Y + (size_t)b * NC * NPIX + (size_t)c0 * NPIX;
  const float* Zb = Z + (size_t)b * NPIX * NK;

  float acc[4][4];
#pragma unroll
  for (int i = 0; i < 4; ++i)
#pragma unroll
    for (int j = 0; j < 4; ++j) acc[i][j] = 0.f;

  for (int nb = nbase; nb < nbase + 512; nb += 32) {
#pragma unroll
    for (int r = 0; r < 2; ++r) {
      int id = t + r * 256;
      int yc = id >> 3, ynq = (id & 7) << 2;
      float4 yv = *(const float4*)(Yb + (size_t)yc * NPIX + nb + ynq);
      Ys[ynq + 0][yc] = yv.x;
      Ys[ynq + 1][yc] = yv.y;
      Ys[ynq + 2][yc] = yv.z;
      Ys[ynq + 3][yc] = yv.w;
      int zn = id >> 4, zkq = (id & 15) << 2;
      *(float4*)&Zs[zn][zkq] =
          *(const float4*)(Zb + (size_t)(nb + zn) * NK + zkq);
    }
    __syncthreads();
#pragma unroll
    for (int nn = 0; nn < 32; ++nn) {
      float4 a = *(float4*)&Ys[nn][ty << 2];
      float4 zk = *(float4*)&Zs[nn][tx << 2];
      float av[4] = {a.x, a.y, a.z, a.w};
      float zv[4] = {zk.x, zk.y, zk.z, zk.w};
#pragma unroll
      for (int i = 0; i < 4; ++i)
#pragma unroll
        for (int j = 0; j < 4; ++j) acc[i][j] = fmaf(av[i], zv[j], acc[i][j]);
    }
    __syncthreads();
  }

  float* Mob = Mraw + ((size_t)b * NC + c0) * NK;
#pragma unroll
  for (int i = 0; i < 4; ++i)
#pragma unroll
    for (int j = 0; j < 4; ++j)
      atomicAdd(&Mob[(size_t)(ty * 4 + i) * NK + tx * 4 + j],
                acc[i][j] * invc[tx * 4 + j]);
}

// ---------------- l2-normalize mu columns from Mraw -> mu_out ----------------
__global__ __launch_bounds__(256) void munorm2(const float* __restrict__ Mraw,
                                               float* __restrict__ Mu) {
  __shared__ float ssp[4][64];
  __shared__ float scale[64];
  const int b = blockIdx.x;
  const int t = threadIdx.x;
  const int k = t & 63, grp = t >> 6;
  const float* Mb = Mraw + (size_t)b * NC * NK;
  float ss = 0.f;
  for (int c = grp * 128; c < grp * 128 + 128; ++c) {
    float v = Mb[(size_t)c * NK + k];
    ss += v * v;
  }
  ssp[grp][k] = ss;
  __syncthreads();
  if (t < 64) {
    float s = ssp[0][t] + ssp[1][t] + ssp[2][t] + ssp[3][t];
    scale[t] = 1.f / (1e-6f + sqrtf(s));
  }
  __syncthreads();
  float* Mo = Mu + (size_t)b * NC * NK;
  for (int i4 = t; i4 < NC * NK / 4; i4 += 256) {
    int idx = i4 * 4;
    int k0 = idx & 63;
    float4 v = *(const float4*)(Mb + idx);
    v.x *= scale[k0 + 0];
    v.y *= scale[k0 + 1];
    v.z *= scale[k0 + 2];
    v.w *= scale[k0 + 3];
    *(float4*)(Mo + idx) = v;
  }
}

// ---------------- reconstruction: xr = relu(mu z^T) -> bf16 hi/lo [b][n][c] ----
__global__ __launch_bounds__(256) void recon(
    const float* __restrict__ Mo, const float* __restrict__ Z,
    ushort* __restrict__ XtHi, ushort* __restrict__ XtLo) {
  __shared__ float Ms[64][68];
  __shared__ float Zs[64][68];
  const int b = blockIdx.z, c0 = blockIdx.y * 64, n0 = blockIdx.x * 64;
  const int t = threadIdx.x, ty = t >> 4, tx = t & 15;
  const float* Mb = Mo + (size_t)b * NC * NK;
  const float* Zb = Z + (size_t)b * NPIX * NK;
#pragma unroll
  for (int r = 0; r < 4; ++r) {
    int id = t + r * 256;
    int rc = id >> 4, kq = (id & 15) << 2;
    float4 mv = *(const float4*)(Mb + (size_t)(c0 + rc) * NK + kq);
    Ms[kq + 0][rc] = mv.x;
    Ms[kq + 1][rc] = mv.y;
    Ms[kq + 2][rc] = mv.z;
    Ms[kq + 3][rc] = mv.w;
    float4 zv = *(const float4*)(Zb + (size_t)(n0 + rc) * NK + kq);
    Zs[kq + 0][rc] = zv.x;
    Zs[kq + 1][rc] = zv.y;
    Zs[kq + 2][rc] = zv.z;
    Zs[kq + 3][rc] = zv.w;
  }
  __syncthreads();
  float acc[4][4];
#pragma unroll
  for (int i = 0; i < 4; ++i)
#pragma unroll
    for (int j = 0; j < 4; ++j) acc[i][j] = 0.f;
#pragma unroll 8
  for (int kk = 0; kk < 64; ++kk) {
    float4 a = *(float4*)&Ms[kk][ty << 2];
    float4 zv4 = *(float4*)&Zs[kk][tx << 2];
    float av[4] = {a.x, a.y, a.z, a.w};
    float zv[4] = {zv4.x, zv4.y, zv4.z, zv4.w};
#pragma unroll
    for (int i = 0; i < 4; ++i)
#pragma unroll
      for (int j = 0; j < 4; ++j) acc[i][j] = fmaf(av[i], zv[j], acc[i][j]);
  }
#pragma unroll
  for (int j = 0; j < 4; ++j) {
    float v0 = fmaxf(acc[0][j], 0.f), v1 = fmaxf(acc[1][j], 0.f);
    float v2 = fmaxf(acc[2][j], 0.f), v3 = fmaxf(acc[3][j], 0.f);
    ushort4 h, l;
    h.x = f2bf(v0); l.x = f2bf(v0 - bf2f(h.x));
    h.y = f2bf(v1); l.y = f2bf(v1 - bf2f(h.y));
    h.z = f2bf(v2); l.z = f2bf(v2 - bf2f(h.z));
    h.w = f2bf(v3); l.w = f2bf(v3 - bf2f(h.w));
    size_t off = ((size_t)b * NPIX + n0 + tx * 4 + j) * NC + c0 + ty * 4;
    *(ushort4*)(XtHi + off) = h;
    *(ushort4*)(XtLo + off) = l;
  }
}

// ---------------- BN stats ----------------
__global__ __launch_bounds__(256) void bn_stats(const float* __restrict__ X2,
                                                float* __restrict__ bsum,
                                                float* __restrict__ bss) {
  const int o = blockIdx.x, b = blockIdx.y;
  const int t = threadIdx.x;
  const float* base = X2 + ((size_t)b * NC + o) * NPIX;
  float s = 0.f, q = 0.f;
#pragma unroll
  for (int r = 0; r < 4; ++r) {
    float4 v = *(const float4*)(base + (size_t)(t + r * 256) * 4);
    s += v.x + v.y + v.z + v.w;
    q += v.x * v.x + v.y * v.y + v.z * v.z + v.w * v.w;
  }
#pragma unroll
  for (int m = 1; m < 64; m <<= 1) {
    s += __shfl_xor(s, m);
    q += __shfl_xor(q, m);
  }
  __shared__ float rs[4], rq[4];
  int w = t >> 6;
  if ((t & 63) == 0) {
    rs[w] = s;
    rq[w] = q;
  }
  __syncthreads();
  if (t == 0) {
    atomicAdd(&bsum[o], rs[0] + rs[1] + rs[2] + rs[3]);
    atomicAdd(&bss[o], rq[0] + rq[1] + rq[2] + rq[3]);
  }
}

// ---------------- BN finalize + residual + relu ----------------
__global__ __launch_bounds__(256) void bn_fin(
    const float* __restrict__ X2, const float* __restrict__ Xin,
    const float* __restrict__ bsum, const float* __restrict__ bss,
    const float* __restrict__ gamma, const float* __restrict__ beta,
    float* __restrict__ out) {
  const size_t total4 = (size_t)NB * NC * NPIX / 4;
  for (size_t i4 = (size_t)blockIdx.x * 256 + threadIdx.x; i4 < total4;
       i4 += (size_t)gridDim.x * 256) {
    size_t i = i4 * 4;
    int o = (int)((i >> 12) & 511);
    float mean = bsum[o] * (1.f / 65536.f);
    float var = bss[o] * (1.f / 65536.f) - mean * mean;
    float inv = rsqrtf(var + 1e-5f) * gamma[o];
    float sh = beta[o] - mean * inv;
    float4 v = *(const float4*)(X2 + i);
    float4 xo = *(const float4*)(Xin + i);
    float4 r;
    r.x = fmaxf(fmaf(v.x, inv, sh) + xo.x, 0.f);
    r.y = fmaxf(fmaf(v.y, inv, sh) + xo.y, 0.f);
    r.z = fmaxf(fmaf(v.z, inv, sh) + xo.z, 0.f);
    r.w = fmaxf(fmaf(v.w, inv, sh) + xo.w, 0.f);
    *(float4*)(out + i) = r;
  }
}

extern "C" void kernel_launch(void* const* d_in, const int* in_sizes, int n_in,
                              void* d_out, int out_size, void* d_ws,
                              size_t ws_size, hipStream_t stream) {
  const float* x = (const float*)d_in[0];
  const float* w1 = (const float*)d_in[1];
  const float* b1 = (const float*)d_in[2];
  const float* w2 = (const float*)d_in[3];
  const float* gamma = (const float*)d_in[4];
  const float* beta = (const float*)d_in[5];
  const float* mu0 = (const float*)d_in[6];

  float* out = (float*)d_out;                     // [16,512,4096]
  float* mu_out = out + (size_t)NB * NC * NPIX;   // [16,512,64]
  float* zt_out = mu_out + (size_t)NB * NC * NK;  // [16,64,4096]

  // Xt bf16 hi/lo scratch overlays the `out` region (dead until bn_fin).
  ushort* XtHi = (ushort*)out;
  ushort* XtLo = XtHi + (size_t)NB * NPIX * NC;

  float* ws = (float*)d_ws;
  float* Y = ws;                                // [16,512,4096] conv out / x2
  float* Z = Y + (size_t)NB * NC * NPIX;        // [16,4096,64]
  float* accbase = Z + (size_t)NB * NPIX * NK;  // colsum[3] | unused | bn
  float* bnsum = accbase + 6 * 1024;
  float* bnss = bnsum + 512;
  ushort* W1hi = (ushort*)(accbase + 8192);
  ushort* W1lo = W1hi + NC * NC;
  ushort* W2hi = W1lo + NC * NC;
  ushort* W2lo = W2hi + NC * NC;
  float* Mraw = (float*)(W2lo + NC * NC);  // [16,512,64] staging

  zero_acc<<<dim3(28), dim3(256), 0, stream>>>(accbase, 7168);
  wsplit<<<dim3(256), dim3(256), 0, stream>>>(w1, W1hi, W1lo);
  wsplit<<<dim3(256), dim3(256), 0, stream>>>(w2, W2hi, W2lo);
  xtsplit<<<dim3(64, 8, 16), dim3(256), 0, stream>>>(x, XtHi, XtLo);

  // conv1: Y = W1 @ x + b1  (MFMA split-bf16)
  gemm_split<<<dim3(32, 4, 16), dim3(256), 0, stream>>>(W1hi, W1lo, XtHi, XtLo,
                                                        b1, Y);

  for (int s = 0; s < 3; ++s) {
    float* cs = accbase + s * 1024;
    const float* mu_in = (s == 0) ? mu0 : mu_out;
    size_t mstride = (s == 0) ? 0 : (size_t)NC * NK;
    estep<<<dim3(64, 16), dim3(256), 0, stream>>>(
        Y, mu_in, mstride, Z, cs, (s == 2) ? zt_out : (float*)nullptr);
    zero_acc<<<dim3(2048), dim3(256), 0, stream>>>(Mraw, NB * NC * NK);
    mstep<<<dim3(8, 16, 8), dim3(256), 0, stream>>>(Y, Z, cs, Mraw);
    munorm2<<<dim3(16), dim3(256), 0, stream>>>(Mraw, mu_out);
  }

  // xr = relu(mu z^T) -> bf16 hi/lo transposed (overwrites Xt region)
  recon<<<dim3(64, 8, 16), dim3(256), 0, stream>>>(mu_out, Z, XtHi, XtLo);

  // conv2: x2 = W2 @ xr -> Y region (free after recon)
  gemm_split<<<dim3(32, 4, 16), dim3(256), 0, stream>>>(W2hi, W2lo, XtHi, XtLo,
                                                        (const float*)nullptr,
                                                        Y);

  bn_stats<<<dim3(512, 16), dim3(256), 0, stream>>>(Y, bnsum, bnss);
  bn_fin<<<dim3(8192), dim3(256), 0, stream>>>(Y, x, bnsum, bnss, gamma, beta,
                                               out);
}

// Round 4
// 1026.270 us; speedup vs baseline: 1.7708x; 1.1797x over previous
//
#include <hip/hip_runtime.h>
#include <math.h>

#define NB 16
#define NC 512
#define NPIX 4096
#define NK 64

typedef __attribute__((ext_vector_type(8))) short short8;
typedef __attribute__((ext_vector_type(4))) float f32x4;

#define GLD16(gp, lp)                                                   \
  __builtin_amdgcn_global_load_lds(                                     \
      (const __attribute__((address_space(1))) void*)(gp),              \
      (__attribute__((address_space(3))) void*)(lp), 16, 0, 0)

__device__ inline ushort f2bf(float f) {
  unsigned u = __float_as_uint(f);
  unsigned r = u + 0x7FFFu + ((u >> 16) & 1u);
  return (ushort)(r >> 16);
}
__device__ inline float bf2f(ushort h) {
  return __uint_as_float((unsigned)h << 16);
}

// ---------------- zero accumulators ----------------
__global__ void zero_acc(float* __restrict__ p, int n) {
  int i = blockIdx.x * 256 + threadIdx.x;
  if (i < n) p[i] = 0.f;
}

// ---------------- W fp32 -> bf16 hi/lo ----------------
__global__ void wsplit(const float* __restrict__ W, ushort* __restrict__ Hi,
                       ushort* __restrict__ Lo) {
  int i = (blockIdx.x * 256 + threadIdx.x) * 4;
  float4 v = *(const float4*)(W + i);
  ushort4 h, l;
  h.x = f2bf(v.x); l.x = f2bf(v.x - bf2f(h.x));
  h.y = f2bf(v.y); l.y = f2bf(v.y - bf2f(h.y));
  h.z = f2bf(v.z); l.z = f2bf(v.z - bf2f(h.z));
  h.w = f2bf(v.w); l.w = f2bf(v.w - bf2f(h.w));
  *(ushort4*)(Hi + i) = h;
  *(ushort4*)(Lo + i) = l;
}

// ---------------- x [b][c][n] fp32 -> Xt [b][n][c] bf16 hi/lo ----------------
__global__ __launch_bounds__(256) void xtsplit(const float* __restrict__ X,
                                               ushort* __restrict__ Hi,
                                               ushort* __restrict__ Lo) {
  __shared__ float T[64][65];
  const int b = blockIdx.z, c0 = blockIdx.y * 64, n0 = blockIdx.x * 64;
  const int t = threadIdx.x;
  const float* Xb = X + ((size_t)b * NC + c0) * NPIX + n0;
#pragma unroll
  for (int r = 0; r < 4; ++r) {
    int lin = t + r * 256;
    int cl = lin >> 4, nq = (lin & 15) * 4;
    float4 v = *(const float4*)(Xb + (size_t)cl * NPIX + nq);
    T[cl][nq + 0] = v.x;
    T[cl][nq + 1] = v.y;
    T[cl][nq + 2] = v.z;
    T[cl][nq + 3] = v.w;
  }
  __syncthreads();
#pragma unroll
  for (int r = 0; r < 4; ++r) {
    int lin = t + r * 256;
    int nl = lin >> 4, cq = (lin & 15) * 4;
    ushort4 h, l;
    float v0 = T[cq + 0][nl], v1 = T[cq + 1][nl], v2 = T[cq + 2][nl],
          v3 = T[cq + 3][nl];
    h.x = f2bf(v0); l.x = f2bf(v0 - bf2f(h.x));
    h.y = f2bf(v1); l.y = f2bf(v1 - bf2f(h.y));
    h.z = f2bf(v2); l.z = f2bf(v2 - bf2f(h.z));
    h.w = f2bf(v3); l.w = f2bf(v3 - bf2f(h.w));
    size_t off = ((size_t)b * NPIX + n0 + nl) * NC + c0 + cq;
    *(ushort4*)(Hi + off) = h;
    *(ushort4*)(Lo + off) = l;
  }
}

// ---------------- split-bf16 MFMA GEMM (conv2): fp32 out ----------------
__global__ __launch_bounds__(256) void gemm_split(
    const ushort* __restrict__ Whi, const ushort* __restrict__ Wlo,
    const ushort* __restrict__ Xhi, const ushort* __restrict__ Xlo,
    float* __restrict__ O) {
  __shared__ short As[128 * 64];
  __shared__ short Bs[128 * 64];
  const int b = blockIdx.z;
  const int m0 = blockIdx.y * 128;
  const int n0 = blockIdx.x * 128;
  const int t = threadIdx.x;
  const int lane = t & 63, wid = t >> 6;
  const int wr = wid >> 1, wc = wid & 1;

  const ushort* Xb_hi = Xhi + (size_t)b * NPIX * NC;
  const ushort* Xb_lo = Xlo + (size_t)b * NPIX * NC;
  const ushort* Asrc[3] = {Whi, Whi, Wlo};
  const ushort* Bsrc[3] = {Xb_hi, Xb_lo, Xb_hi};

  f32x4 acc[4][4];
#pragma unroll
  for (int i = 0; i < 4; ++i)
#pragma unroll
    for (int j = 0; j < 4; ++j) acc[i][j] = (f32x4){0.f, 0.f, 0.f, 0.f};

  const int s_r = lane >> 3;
  const int s_p = lane & 7;

  for (int p = 0; p < 3; ++p) {
    const ushort* Ap = Asrc[p];
    const ushort* Bp = Bsrc[p];
    for (int k0 = 0; k0 < NC; k0 += 64) {
#pragma unroll
      for (int i = 0; i < 4; ++i) {
        int ch = wid * 4 + i;
        int r = ch * 8 + s_r;
        int ls = s_p ^ (r & 7);
        GLD16(Ap + (size_t)(m0 + r) * NC + k0 + ls * 8, (short*)As + ch * 512);
        GLD16(Bp + (size_t)(n0 + r) * NC + k0 + ls * 8, (short*)Bs + ch * 512);
      }
      __syncthreads();
#pragma unroll
      for (int kk = 0; kk < 2; ++kk) {
        short8 af[4], bfr[4];
#pragma unroll
        for (int i = 0; i < 4; ++i) {
          int row = wr * 64 + i * 16 + (lane & 15);
          int ph = (kk * 4 + (lane >> 4)) ^ (row & 7);
          af[i] = *(const short8*)(As + row * 64 + ph * 8);
          int col = wc * 64 + i * 16 + (lane & 15);
          int phb = (kk * 4 + (lane >> 4)) ^ (col & 7);
          bfr[i] = *(const short8*)(Bs + col * 64 + phb * 8);
        }
#pragma unroll
        for (int i = 0; i < 4; ++i)
#pragma unroll
          for (int j = 0; j < 4; ++j)
            acc[i][j] = __builtin_amdgcn_mfma_f32_16x16x32_bf16(
                af[i], bfr[j], acc[i][j], 0, 0, 0);
      }
      __syncthreads();
    }
  }

  float* Ob = O + (size_t)b * NC * NPIX;
  const int cb = n0 + wc * 64 + (lane & 15);
  const int rb = m0 + wr * 64 + (lane >> 4) * 4;
#pragma unroll
  for (int i = 0; i < 4; ++i) {
#pragma unroll
    for (int q = 0; q < 4; ++q) {
      int r = rb + i * 16 + q;
      float* orow = Ob + (size_t)r * NPIX;
#pragma unroll
      for (int j = 0; j < 4; ++j) orow[cb + j * 16] = acc[i][j][q];
    }
  }
}

// ---------------- conv1: split GEMM, emits Y as bf16 hi/lo in BOTH layouts ---
__global__ __launch_bounds__(256) void gemm_split_y(
    const ushort* __restrict__ Whi, const ushort* __restrict__ Wlo,
    const ushort* __restrict__ Xhi, const ushort* __restrict__ Xlo,
    const float* __restrict__ bias, ushort* __restrict__ YtHi,
    ushort* __restrict__ YtLo, ushort* __restrict__ YcHi,
    ushort* __restrict__ YcLo) {
  __shared__ short As[128 * 64];
  __shared__ short Bs[128 * 64];
  const int b = blockIdx.z;
  const int m0 = blockIdx.y * 128;
  const int n0 = blockIdx.x * 128;
  const int t = threadIdx.x;
  const int lane = t & 63, wid = t >> 6;
  const int wr = wid >> 1, wc = wid & 1;

  const ushort* Xb_hi = Xhi + (size_t)b * NPIX * NC;
  const ushort* Xb_lo = Xlo + (size_t)b * NPIX * NC;
  const ushort* Asrc[3] = {Whi, Whi, Wlo};
  const ushort* Bsrc[3] = {Xb_hi, Xb_lo, Xb_hi};

  f32x4 acc[4][4];
#pragma unroll
  for (int i = 0; i < 4; ++i)
#pragma unroll
    for (int j = 0; j < 4; ++j) acc[i][j] = (f32x4){0.f, 0.f, 0.f, 0.f};

  const int s_r = lane >> 3;
  const int s_p = lane & 7;

  for (int p = 0; p < 3; ++p) {
    const ushort* Ap = Asrc[p];
    const ushort* Bp = Bsrc[p];
    for (int k0 = 0; k0 < NC; k0 += 64) {
#pragma unroll
      for (int i = 0; i < 4; ++i) {
        int ch = wid * 4 + i;
        int r = ch * 8 + s_r;
        int ls = s_p ^ (r & 7);
        GLD16(Ap + (size_t)(m0 + r) * NC + k0 + ls * 8, (short*)As + ch * 512);
        GLD16(Bp + (size_t)(n0 + r) * NC + k0 + ls * 8, (short*)Bs + ch * 512);
      }
      __syncthreads();
#pragma unroll
      for (int kk = 0; kk < 2; ++kk) {
        short8 af[4], bfr[4];
#pragma unroll
        for (int i = 0; i < 4; ++i) {
          int row = wr * 64 + i * 16 + (lane & 15);
          int ph = (kk * 4 + (lane >> 4)) ^ (row & 7);
          af[i] = *(const short8*)(As + row * 64 + ph * 8);
          int col = wc * 64 + i * 16 + (lane & 15);
          int phb = (kk * 4 + (lane >> 4)) ^ (col & 7);
          bfr[i] = *(const short8*)(Bs + col * 64 + phb * 8);
        }
#pragma unroll
        for (int i = 0; i < 4; ++i)
#pragma unroll
          for (int j = 0; j < 4; ++j)
            acc[i][j] = __builtin_amdgcn_mfma_f32_16x16x32_bf16(
                af[i], bfr[j], acc[i][j], 0, 0, 0);
      }
      __syncthreads();
    }
  }

  ushort* YcH = YcHi + (size_t)b * NC * NPIX;
  ushort* YcL = YcLo + (size_t)b * NC * NPIX;
  ushort* YtH = YtHi + (size_t)b * NPIX * NC;
  ushort* YtL = YtLo + (size_t)b * NPIX * NC;
  const int crow0 = m0 + wr * 64 + (lane >> 4) * 4;  // + i*16 + q
  const int ncol0 = n0 + wc * 64 + (lane & 15);      // + j*16
#pragma unroll
  for (int i = 0; i < 4; ++i) {
#pragma unroll
    for (int j = 0; j < 4; ++j) {
      int n = ncol0 + j * 16;
      ushort4 hv, lv;
#pragma unroll
      for (int q = 0; q < 4; ++q) {
        int c = crow0 + i * 16 + q;
        float v = acc[i][j][q] + bias[c];
        ushort h = f2bf(v);
        ushort l = f2bf(v - bf2f(h));
        ((ushort*)&hv)[q] = h;
        ((ushort*)&lv)[q] = l;
        YcH[(size_t)c * NPIX + n] = h;
        YcL[(size_t)c * NPIX + n] = l;
      }
      *(ushort4*)(YtH + (size_t)n * NC + crow0 + i * 16) = hv;
      *(ushort4*)(YtL + (size_t)n * NC + crow0 + i * 16) = lv;
    }
  }
}

// ---------------- mu [c][k] fp32 -> muT [b][k][c] bf16 hi/lo ----------------
__global__ __launch_bounds__(256) void mutprep(const float* __restrict__ mu,
                                               size_t bstride,
                                               ushort* __restrict__ muTHi,
                                               ushort* __restrict__ muTLo) {
  __shared__ float T[64][65];
  const int b = blockIdx.y, c0 = blockIdx.x * 64;
  const int t = threadIdx.x;
  const float* mub = mu + (size_t)b * bstride;
  for (int e = t; e < 4096; e += 256) {
    int c = e >> 6, k = e & 63;
    T[c][k] = mub[(size_t)(c0 + c) * NK + k];
  }
  __syncthreads();
  for (int e = t; e < 4096; e += 256) {
    int k = e >> 6, c = e & 63;
    float v = T[c][k];
    ushort h = f2bf(v);
    muTHi[((size_t)b * NK + k) * NC + c0 + c] = h;
    muTLo[((size_t)b * NK + k) * NC + c0 + c] = f2bf(v - bf2f(h));
  }
}

// ---------------- E-step (MFMA): S = Yt muT^T, softmax, zT hi/lo + colsum ----
__global__ __launch_bounds__(256) void estep_mfma(
    const ushort* __restrict__ YtHi, const ushort* __restrict__ YtLo,
    const ushort* __restrict__ muTHi, const ushort* __restrict__ muTLo,
    ushort* __restrict__ zTHi, ushort* __restrict__ zTLo,
    float* __restrict__ colsum, float* __restrict__ zt_out) {
  __shared__ char smem[49408];
  short* Ahi = (short*)smem;       // [128][64] swizzled
  short* Alo = Ahi + 128 * 64;
  short* Bhi = Alo + 128 * 64;     // [64][64] swizzled
  short* Blo = Bhi + 64 * 64;
  const int b = blockIdx.y, n0 = blockIdx.x * 128;
  const int t = threadIdx.x, lane = t & 63, wid = t >> 6;
  const ushort* YtH = YtHi + ((size_t)b * NPIX + n0) * NC;
  const ushort* YtL = YtLo + ((size_t)b * NPIX + n0) * NC;
  const ushort* mH = muTHi + (size_t)b * NK * NC;
  const ushort* mL = muTLo + (size_t)b * NK * NC;

  f32x4 acc[2][4];
#pragma unroll
  for (int i = 0; i < 2; ++i)
#pragma unroll
    for (int j = 0; j < 4; ++j) acc[i][j] = (f32x4){0.f, 0.f, 0.f, 0.f};

  const int s_r8 = lane >> 3, s_p = lane & 7;
  for (int c0 = 0; c0 < NC; c0 += 64) {
#pragma unroll
    for (int i = 0; i < 4; ++i) {
      int ch = wid * 4 + i;
      int r = ch * 8 + s_r8;
      int ls = s_p ^ (r & 7);
      GLD16(YtH + (size_t)r * NC + c0 + ls * 8, Ahi + ch * 512);
      GLD16(YtL + (size_t)r * NC + c0 + ls * 8, Alo + ch * 512);
    }
#pragma unroll
    for (int i = 0; i < 2; ++i) {
      int ch = wid * 2 + i;
      int r = ch * 8 + s_r8;
      int ls = s_p ^ (r & 7);
      GLD16(mH + (size_t)r * NC + c0 + ls * 8, Bhi + ch * 512);
      GLD16(mL + (size_t)r * NC + c0 + ls * 8, Blo + ch * 512);
    }
    __syncthreads();
#pragma unroll
    for (int p = 0; p < 3; ++p) {
      const short* Ap = (p == 1) ? Alo : Ahi;
      const short* Bp = (p == 2) ? Blo : Bhi;
#pragma unroll
      for (int kk = 0; kk < 2; ++kk) {
        short8 af[2], bfr[4];
#pragma unroll
        for (int i = 0; i < 2; ++i) {
          int row = wid * 32 + i * 16 + (lane & 15);
          int ph = (kk * 4 + (lane >> 4)) ^ (row & 7);
          af[i] = *(const short8*)(Ap + row * 64 + ph * 8);
        }
#pragma unroll
        for (int j = 0; j < 4; ++j) {
          int row = j * 16 + (lane & 15);
          int ph = (kk * 4 + (lane >> 4)) ^ (row & 7);
          bfr[j] = *(const short8*)(Bp + row * 64 + ph * 8);
        }
#pragma unroll
        for (int i = 0; i < 2; ++i)
#pragma unroll
          for (int j = 0; j < 4; ++j)
            acc[i][j] = __builtin_amdgcn_mfma_f32_16x16x32_bf16(
                af[i], bfr[j], acc[i][j], 0, 0, 0);
      }
    }
    __syncthreads();
  }

  // softmax over k (64) per n-row; row = wid*32 + i*16 + (lane>>4)*4 + q
  float z[2][4][4];
#pragma unroll
  for (int i = 0; i < 2; ++i) {
#pragma unroll
    for (int q = 0; q < 4; ++q) {
      float mx = -1e30f;
#pragma unroll
      for (int j = 0; j < 4; ++j) mx = fmaxf(mx, acc[i][j][q]);
      mx = fmaxf(mx, __shfl_xor(mx, 1));
      mx = fmaxf(mx, __shfl_xor(mx, 2));
      mx = fmaxf(mx, __shfl_xor(mx, 4));
      mx = fmaxf(mx, __shfl_xor(mx, 8));
      float s = 0.f;
#pragma unroll
      for (int j = 0; j < 4; ++j) {
        z[i][j][q] = __expf(acc[i][j][q] - mx);
        s += z[i][j][q];
      }
      s += __shfl_xor(s, 1);
      s += __shfl_xor(s, 2);
      s += __shfl_xor(s, 4);
      s += __shfl_xor(s, 8);
      float inv = 1.f / s;
#pragma unroll
      for (int j = 0; j < 4; ++j) z[i][j][q] *= inv;
    }
  }

  // LDS reuse: zls[64][136] hi/lo + cs[64]
  ushort* zlsH = (ushort*)smem;
  ushort* zlsL = zlsH + 64 * 136;
  float* cs = (float*)(smem + 4 * 64 * 136);  // 34816
  if (t < 64) cs[t] = 0.f;
  const int ln0 = wid * 32 + (lane >> 4) * 4;
#pragma unroll
  for (int i = 0; i < 2; ++i)
#pragma unroll
    for (int j = 0; j < 4; ++j) {
      int k = j * 16 + (lane & 15);
#pragma unroll
      for (int q = 0; q < 4; ++q) {
        int ln = ln0 + i * 16 + q;
        float v = z[i][j][q];
        ushort h = f2bf(v);
        zlsH[k * 136 + ln] = h;
        zlsL[k * 136 + ln] = f2bf(v - bf2f(h));
      }
    }
  __syncthreads();
#pragma unroll
  for (int j = 0; j < 4; ++j) {
    float pcs = 0.f;
#pragma unroll
    for (int i = 0; i < 2; ++i)
#pragma unroll
      for (int q = 0; q < 4; ++q) pcs += z[i][j][q];
    atomicAdd(&cs[j * 16 + (lane & 15)], pcs);
  }
  __syncthreads();
  if (t < 64) atomicAdd(&colsum[b * NK + t], cs[t]);

  for (int e = t; e < 1024; e += 256) {  // 64 rows x 16 groups of 8 ushort
    int k = e >> 4, off = (e & 15) * 8;
    short8 h = *(const short8*)(zlsH + k * 136 + off);
    short8 l = *(const short8*)(zlsL + k * 136 + off);
    *(short8*)(zTHi + ((size_t)b * NK + k) * NPIX + n0 + off) = h;
    *(short8*)(zTLo + ((size_t)b * NK + k) * NPIX + n0 + off) = l;
  }
  if (zt_out) {
    for (int e = t; e < 2048; e += 256) {  // 64 x 128 floats, groups of 4
      int k = e >> 5, off = (e & 31) * 4;
      float4 v;
      v.x = bf2f(zlsH[k * 136 + off + 0]) + bf2f(zlsL[k * 136 + off + 0]);
      v.y = bf2f(zlsH[k * 136 + off + 1]) + bf2f(zlsL[k * 136 + off + 1]);
      v.z = bf2f(zlsH[k * 136 + off + 2]) + bf2f(zlsL[k * 136 + off + 2]);
      v.w = bf2f(zlsH[k * 136 + off + 3]) + bf2f(zlsL[k * 136 + off + 3]);
      *(float4*)(zt_out + ((size_t)b * NK + k) * NPIX + n0 + off) = v;
    }
  }
}

// ---------------- M-step (MFMA): Mraw[c][k] += Yc z_ via split-n ------------
__global__ __launch_bounds__(256) void mstep_mfma(
    const ushort* __restrict__ YcHi, const ushort* __restrict__ YcLo,
    const ushort* __restrict__ zTHi, const ushort* __restrict__ zTLo,
    const float* __restrict__ colsum, float* __restrict__ Mraw) {
  __shared__ char smem[49152];
  short* Ahi = (short*)smem;
  short* Alo = Ahi + 128 * 64;
  short* Bhi = Alo + 128 * 64;
  short* Blo = Bhi + 64 * 64;
  const int b = blockIdx.y, c0t = blockIdx.x * 128, nbase = blockIdx.z * 512;
  const int t = threadIdx.x, lane = t & 63, wid = t >> 6;
  const ushort* AH = YcHi + ((size_t)b * NC + c0t) * NPIX;
  const ushort* AL = YcLo + ((size_t)b * NC + c0t) * NPIX;
  const ushort* BH = zTHi + (size_t)b * NK * NPIX;
  const ushort* BL = zTLo + (size_t)b * NK * NPIX;

  f32x4 acc[2][4];
#pragma unroll
  for (int i = 0; i < 2; ++i)
#pragma unroll
    for (int j = 0; j < 4; ++j) acc[i][j] = (f32x4){0.f, 0.f, 0.f, 0.f};

  const int s_r8 = lane >> 3, s_p = lane & 7;
  for (int nc = 0; nc < 512; nc += 64) {
    int noff = nbase + nc;
#pragma unroll
    for (int i = 0; i < 4; ++i) {
      int ch = wid * 4 + i;
      int r = ch * 8 + s_r8;
      int ls = s_p ^ (r & 7);
      GLD16(AH + (size_t)r * NPIX + noff + ls * 8, Ahi + ch * 512);
      GLD16(AL + (size_t)r * NPIX + noff + ls * 8, Alo + ch * 512);
    }
#pragma unroll
    for (int i = 0; i < 2; ++i) {
      int ch = wid * 2 + i;
      int r = ch * 8 + s_r8;
      int ls = s_p ^ (r & 7);
      GLD16(BH + (size_t)r * NPIX + noff + ls * 8, Bhi + ch * 512);
      GLD16(BL + (size_t)r * NPIX + noff + ls * 8, Blo + ch * 512);
    }
    __syncthreads();
#pragma unroll
    for (int p = 0; p < 3; ++p) {
      const short* Ap = (p == 1) ? Alo : Ahi;
      const short* Bp = (p == 2) ? Blo : Bhi;
#pragma unroll
      for (int kk = 0; kk < 2; ++kk) {
        short8 af[2], bfr[4];
#pragma unroll
        for (int i = 0; i < 2; ++i) {
          int row = wid * 32 + i * 16 + (lane & 15);
          int ph = (kk * 4 + (lane >> 4)) ^ (row & 7);
          af[i] = *(const short8*)(Ap + row * 64 + ph * 8);
        }
#pragma unroll
        for (int j = 0; j < 4; ++j) {
          int row = j * 16 + (lane & 15);
          int ph = (kk * 4 + (lane >> 4)) ^ (row & 7);
          bfr[j] = *(const short8*)(Bp + row * 64 + ph * 8);
        }
#pragma unroll
        for (int i = 0; i < 2; ++i)
#pragma unroll
          for (int j = 0; j < 4; ++j)
            acc[i][j] = __builtin_amdgcn_mfma_f32_16x16x32_bf16(
                af[i], bfr[j], acc[i][j], 0, 0, 0);
      }
    }
    __syncthreads();
  }

  float invc[4];
#pragma unroll
  for (int j = 0; j < 4; ++j)
    invc[j] = 1.f / (1e-6f + colsum[b * NK + j * 16 + (lane & 15)]);
  float* Mb = Mraw + ((size_t)b * NC + c0t) * NK;
#pragma unroll
  for (int i = 0; i < 2; ++i)
#pragma unroll
    for (int j = 0; j < 4; ++j) {
      int k = j * 16 + (lane & 15);
#pragma unroll
      for (int q = 0; q < 4; ++q) {
        int cl = wid * 32 + i * 16 + (lane >> 4) * 4 + q;
        atomicAdd(&Mb[(size_t)cl * NK + k], acc[i][j][q] * invc[j]);
      }
    }
}

// ---------------- mu norm phase A: ssq[b][k] = sum_c Mraw^2 ----------------
__global__ __launch_bounds__(256) void munormA(const float* __restrict__ Mraw,
                                               float* __restrict__ ssq) {
  __shared__ float sp[4][64];
  const int b = blockIdx.x, c0 = blockIdx.y * 64;
  const int t = threadIdx.x;
  const int k = t & 63, g = t >> 6;
  const float* Mb = Mraw + (size_t)b * NC * NK;
  float s = 0.f;
  for (int c = c0 + g * 16; c < c0 + g * 16 + 16; ++c) {
    float v = Mb[(size_t)c * NK + k];
    s += v * v;
  }
  sp[g][k] = s;
  __syncthreads();
  if (t < 64) atomicAdd(&ssq[b * NK + t], sp[0][t] + sp[1][t] + sp[2][t] + sp[3][t]);
}

// ---------------- mu norm phase B: mu_out = Mraw / (1e-6+||.||) -------------
__global__ void munormB(const float* __restrict__ Mraw,
                        const float* __restrict__ ssq, float* __restrict__ Mu) {
  int i = blockIdx.x * 256 + threadIdx.x;
  int k = i & 63;
  int b = i >> 15;
  Mu[i] = Mraw[i] * (1.f / (1e-6f + sqrtf(ssq[b * NK + k])));
}

// ---------------- reconstruction: xr = relu(mu z^T) -> Xt bf16 hi/lo --------
__global__ __launch_bounds__(256) void recon(
    const float* __restrict__ Mo, const ushort* __restrict__ zTHi,
    const ushort* __restrict__ zTLo, ushort* __restrict__ XtHi,
    ushort* __restrict__ XtLo) {
  __shared__ float Ms[64][68];
  __shared__ float Zs[64][68];
  const int b = blockIdx.z, c0 = blockIdx.y * 64, n0 = blockIdx.x * 64;
  const int t = threadIdx.x, ty = t >> 4, tx = t & 15;
  const float* Mb = Mo + (size_t)b * NC * NK;
  const ushort* ZH = zTHi + (size_t)b * NK * NPIX;
  const ushort* ZL = zTLo + (size_t)b * NK * NPIX;
#pragma unroll
  for (int r = 0; r < 4; ++r) {
    int id = t + r * 256;
    int rc = id >> 4, kq = (id & 15) << 2;
    float4 mv = *(const float4*)(Mb + (size_t)(c0 + rc) * NK + kq);
    Ms[kq + 0][rc] = mv.x;
    Ms[kq + 1][rc] = mv.y;
    Ms[kq + 2][rc] = mv.z;
    Ms[kq + 3][rc] = mv.w;
    ushort4 h = *(const ushort4*)(ZH + (size_t)rc * NPIX + n0 + kq);
    ushort4 l = *(const ushort4*)(ZL + (size_t)rc * NPIX + n0 + kq);
    Zs[rc][kq + 0] = bf2f(h.x) + bf2f(l.x);
    Zs[rc][kq + 1] = bf2f(h.y) + bf2f(l.y);
    Zs[rc][kq + 2] = bf2f(h.z) + bf2f(l.z);
    Zs[rc][kq + 3] = bf2f(h.w) + bf2f(l.w);
  }
  __syncthreads();
  float acc[4][4];
#pragma unroll
  for (int i = 0; i < 4; ++i)
#pragma unroll
    for (int j = 0; j < 4; ++j) acc[i][j] = 0.f;
#pragma unroll 8
  for (int kk = 0; kk < 64; ++kk) {
    float4 a = *(float4*)&Ms[kk][ty << 2];
    float4 zv4 = *(float4*)&Zs[kk][tx << 2];
    float av[4] = {a.x, a.y, a.z, a.w};
    float zv[4] = {zv4.x, zv4.y, zv4.z, zv4.w};
#pragma unroll
    for (int i = 0; i < 4; ++i)
#pragma unroll
      for (int j = 0; j < 4; ++j) acc[i][j] = fmaf(av[i], zv[j], acc[i][j]);
  }
#pragma unroll
  for (int j = 0; j < 4; ++j) {
    float v0 = fmaxf(acc[0][j], 0.f), v1 = fmaxf(acc[1][j], 0.f);
    float v2 = fmaxf(acc[2][j], 0.f), v3 = fmaxf(acc[3][j], 0.f);
    ushort4 h, l;
    h.x = f2bf(v0); l.x = f2bf(v0 - bf2f(h.x));
    h.y = f2bf(v1); l.y = f2bf(v1 - bf2f(h.y));
    h.z = f2bf(v2); l.z = f2bf(v2 - bf2f(h.z));
    h.w = f2bf(v3); l.w = f2bf(v3 - bf2f(h.w));
    size_t off = ((size_t)b * NPIX + n0 + tx * 4 + j) * NC + c0 + ty * 4;
    *(ushort4*)(XtHi + off) = h;
    *(ushort4*)(XtLo + off) = l;
  }
}

// ---------------- BN stats ----------------
__global__ __launch_bounds__(256) void bn_stats(const float* __restrict__ X2,
                                                float* __restrict__ bsum,
                                                float* __restrict__ bss) {
  const int o = blockIdx.x, b = blockIdx.y;
  const int t = threadIdx.x;
  const float* base = X2 + ((size_t)b * NC + o) * NPIX;
  float s = 0.f, q = 0.f;
#pragma unroll
  for (int r = 0; r < 4; ++r) {
    float4 v = *(const float4*)(base + (size_t)(t + r * 256) * 4);
    s += v.x + v.y + v.z + v.w;
    q += v.x * v.x + v.y * v.y + v.z * v.z + v.w * v.w;
  }
#pragma unroll
  for (int m = 1; m < 64; m <<= 1) {
    s += __shfl_xor(s, m);
    q += __shfl_xor(q, m);
  }
  __shared__ float rs[4], rq[4];
  int w = t >> 6;
  if ((t & 63) == 0) {
    rs[w] = s;
    rq[w] = q;
  }
  __syncthreads();
  if (t == 0) {
    atomicAdd(&bsum[o], rs[0] + rs[1] + rs[2] + rs[3]);
    atomicAdd(&bss[o], rq[0] + rq[1] + rq[2] + rq[3]);
  }
}

// ---------------- BN finalize + residual + relu ----------------
__global__ __launch_bounds__(256) void bn_fin(
    const float* __restrict__ X2, const float* __restrict__ Xin,
    const float* __restrict__ bsum, const float* __restrict__ bss,
    const float* __restrict__ gamma, const float* __restrict__ beta,
    float* __restrict__ out) {
  const size_t total4 = (size_t)NB * NC * NPIX / 4;
  for (size_t i4 = (size_t)blockIdx.x * 256 + threadIdx.x; i4 < total4;
       i4 += (size_t)gridDim.x * 256) {
    size_t i = i4 * 4;
    int o = (int)((i >> 12) & 511);
    float mean = bsum[o] * (1.f / 65536.f);
    float var = bss[o] * (1.f / 65536.f) - mean * mean;
    float inv = rsqrtf(var + 1e-5f) * gamma[o];
    float sh = beta[o] - mean * inv;
    float4 v = *(const float4*)(X2 + i);
    float4 xo = *(const float4*)(Xin + i);
    float4 r;
    r.x = fmaxf(fmaf(v.x, inv, sh) + xo.x, 0.f);
    r.y = fmaxf(fmaf(v.y, inv, sh) + xo.y, 0.f);
    r.z = fmaxf(fmaf(v.z, inv, sh) + xo.z, 0.f);
    r.w = fmaxf(fmaf(v.w, inv, sh) + xo.w, 0.f);
    *(float4*)(out + i) = r;
  }
}

extern "C" void kernel_launch(void* const* d_in, const int* in_sizes, int n_in,
                              void* d_out, int out_size, void* d_ws,
                              size_t ws_size, hipStream_t stream) {
  const float* x = (const float*)d_in[0];
  const float* w1 = (const float*)d_in[1];
  const float* b1 = (const float*)d_in[2];
  const float* w2 = (const float*)d_in[3];
  const float* gamma = (const float*)d_in[4];
  const float* beta = (const float*)d_in[5];
  const float* mu0 = (const float*)d_in[6];

  float* out = (float*)d_out;                     // [16,512,4096]
  float* mu_out = out + (size_t)NB * NC * NPIX;   // [16,512,64]
  float* zt_out = mu_out + (size_t)NB * NC * NK;  // [16,64,4096]

  // Xt bf16 hi/lo overlays `out` (dead until bn_fin).
  ushort* XtHi = (ushort*)out;
  ushort* XtLo = XtHi + (size_t)NB * NPIX * NC;

  // workspace layout
  ushort* YtHi = (ushort*)d_ws;                      // 64 MB each
  ushort* YtLo = YtHi + (size_t)NB * NPIX * NC;
  ushort* YcHi = YtLo + (size_t)NB * NPIX * NC;
  ushort* YcLo = YcHi + (size_t)NB * NPIX * NC;
  ushort* zTHi = YcLo + (size_t)NB * NPIX * NC;      // 8 MB each
  ushort* zTLo = zTHi + (size_t)NB * NK * NPIX;
  ushort* muTHi = zTLo + (size_t)NB * NK * NPIX;     // 1 MB each
  ushort* muTLo = muTHi + (size_t)NB * NK * NC;
  ushort* W1hi = muTLo + (size_t)NB * NK * NC;       // 512 KB each
  ushort* W1lo = W1hi + NC * NC;
  ushort* W2hi = W1lo + NC * NC;
  ushort* W2lo = W2hi + NC * NC;
  float* accbase = (float*)(W2lo + NC * NC);  // colsum[3*1024]|ssq[3*1024]|bn
  float* bnsum = accbase + 6144;
  float* bnss = accbase + 6656;
  float* Mraw = accbase + 7168;  // [16,512,64]
  // conv2 fp32 output reuses the (then-dead) Yt/Yc region
  float* X2 = (float*)YtHi;

  zero_acc<<<dim3(28), dim3(256), 0, stream>>>(accbase, 7168);
  wsplit<<<dim3(256), dim3(256), 0, stream>>>(w1, W1hi, W1lo);
  wsplit<<<dim3(256), dim3(256), 0, stream>>>(w2, W2hi, W2lo);
  xtsplit<<<dim3(64, 8, 16), dim3(256), 0, stream>>>(x, XtHi, XtLo);

  // conv1 -> Yt/Yc bf16 hi/lo (no fp32 Y)
  gemm_split_y<<<dim3(32, 4, 16), dim3(256), 0, stream>>>(
      W1hi, W1lo, XtHi, XtLo, b1, YtHi, YtLo, YcHi, YcLo);

  for (int s = 0; s < 3; ++s) {
    float* cs = accbase + s * 1024;
    float* sq = accbase + 3072 + s * 1024;
    const float* mu_in = (s == 0) ? mu0 : mu_out;
    size_t mstride = (s == 0) ? 0 : (size_t)NC * NK;
    mutprep<<<dim3(8, 16), dim3(256), 0, stream>>>(mu_in, mstride, muTHi,
                                                   muTLo);
    estep_mfma<<<dim3(32, 16), dim3(256), 0, stream>>>(
        YtHi, YtLo, muTHi, muTLo, zTHi, zTLo, cs,
        (s == 2) ? zt_out : (float*)nullptr);
    zero_acc<<<dim3(2048), dim3(256), 0, stream>>>(Mraw, NB * NC * NK);
    mstep_mfma<<<dim3(4, 16, 8), dim3(256), 0, stream>>>(YcHi, YcLo, zTHi,
                                                         zTLo, cs, Mraw);
    munormA<<<dim3(16, 8), dim3(256), 0, stream>>>(Mraw, sq);
    munormB<<<dim3(2048), dim3(256), 0, stream>>>(Mraw, sq, mu_out);
  }

  // xr = relu(mu z^T) -> Xt bf16 hi/lo (overlays out region)
  recon<<<dim3(64, 8, 16), dim3(256), 0, stream>>>(mu_out, zTHi, zTLo, XtHi,
                                                   XtLo);

  // conv2: X2 = W2 @ xr -> ws (Yt/Yc region, now dead)
  gemm_split<<<dim3(32, 4, 16), dim3(256), 0, stream>>>(W2hi, W2lo, XtHi, XtLo,
                                                        X2);

  bn_stats<<<dim3(512, 16), dim3(256), 0, stream>>>(X2, bnsum, bnss);
  bn_fin<<<dim3(8192), dim3(256), 0, stream>>>(X2, x, bnsum, bnss, gamma, beta,
                                               out);
}